// Round 1
// baseline (8121.394 us; speedup 1.0000x reference)
//
#include <hip/hip_runtime.h>
#include <math.h>

#define NP    520
#define NN    (520*520)
#define HH    512
#define NPIX  (512*512)
#define NB    16
#define NPAIR 8
#define ND    4
#define NF    24
#define TWO_PI 6.283185307179586f

__device__ __forceinline__ int wrap520(int t){ t %= NP; return t < 0 ? t + NP : t; }

// ---------- DFT matrices: Wf = exp(-2pi i mk/520), Wi = conj(Wf)/520 ----------
__global__ __launch_bounds__(256) void build_W_k(float* __restrict__ Wfre, float* __restrict__ Wfim,
                                                 float* __restrict__ Wire, float* __restrict__ Wiim){
  int idx = blockIdx.x*256 + threadIdx.x;
  if (idx >= NN) return;
  int m = idx / NP, k = idx % NP;
  int r = (int)(((long long)m * (long long)k) % NP);
  float ang = TWO_PI * (float)r / (float)NP;
  float s, c; sincosf(ang, &s, &c);
  Wfre[idx] = c;             Wfim[idx] = -s;
  Wire[idx] = c * (1.0f/NP); Wiim[idx] = s * (1.0f/NP);
}

// ---------- 5-tap twiddle table for the reg-filter OTFs ----------
__global__ __launch_bounds__(256) void build_e5_k(float* __restrict__ e5re, float* __restrict__ e5im){
  int idx = blockIdx.x*256 + threadIdx.x;
  if (idx >= NP*5) return;
  int u = idx / 5, i = idx % 5;
  int r = wrap520(u * (i - 2));
  float ang = TWO_PI * (float)r / (float)NP;
  float s, c; sincosf(ang, &s, &c);
  e5re[idx] = c; e5im[idx] = -s;
}

// ---------- blur OTF: direct 81-term DFT with center shift (-4,-4) ----------
__global__ __launch_bounds__(256) void build_otf_k(const float* __restrict__ bk,
                                                   float* __restrict__ otfre, float* __restrict__ otfim){
  int idx = blockIdx.x*256 + threadIdx.x;
  if (idx >= NN) return;
  int u = idx / NP, v = idx % NP;
  float ar = 0.f, ai = 0.f;
  for (int i = 0; i < 9; ++i)
    for (int j = 0; j < 9; ++j){
      int r = wrap520(u*(i-4) + v*(j-4));
      float ang = TWO_PI * (float)r / (float)NP;
      float s, c; sincosf(ang, &s, &c);
      float w = bk[i*9+j];
      ar += w * c; ai -= w * s;
    }
  otfre[idx] = ar; otfim[idx] = ai;
}

// ---------- edge-taper autocorrelations r_row[0..8], r_col[0..8] ----------
__global__ void taper_r_k(const float* __restrict__ bk, float* __restrict__ r_row, float* __restrict__ r_col){
  int t = threadIdx.x;
  if (t >= 18) return;
  int k = t % 9;
  bool rowp = (t < 9);
  float proj[9];
  for (int m = 0; m < 9; ++m){
    float a = 0.f;
    for (int j = 0; j < 9; ++j) a += rowp ? bk[m*9+j] : bk[j*9+m];
    proj[m] = a;
  }
  float acc = 0.f;
  for (int m = 0; m + k < 9; ++m) acc += proj[m] * proj[m+k];
  (rowp ? r_row : r_col)[k] = acc;
}

// ---------- weight normalization: zero-mean + L2 norm * scale ----------
__global__ void norm_w_k(const float* __restrict__ cw, const float* __restrict__ scale,
                         float* __restrict__ wn){
  int idx = blockIdx.x*blockDim.x + threadIdx.x;
  if (idx >= ND*NF) return;
  const float* wp = cw + idx*25;
  float mean = 0.f;
  for (int k = 0; k < 25; ++k) mean += wp[k];
  mean *= (1.0f/25.0f);
  float ss = 0.f;
  for (int k = 0; k < 25; ++k){ float d = wp[k]-mean; ss += d*d; }
  float sc = scale[idx] / sqrtf(ss);
  for (int k = 0; k < 25; ++k) wn[idx*25+k] = (wp[k]-mean)*sc;
}

// ---------- S(d,u,v) = sum_f |G_{d,f}(u,v)|^2 ----------
__global__ __launch_bounds__(256) void S_k(const float* __restrict__ wn,
                                           const float* __restrict__ e5re, const float* __restrict__ e5im,
                                           float* __restrict__ Sarr){
  int idx = blockIdx.x*256 + threadIdx.x;
  if (idx >= ND*NN) return;
  int d = idx / NN, p = idx % NN;
  int u = p / NP, v = p % NP;
  float eur[5], eui[5], evr[5], evi[5];
  #pragma unroll
  for (int i = 0; i < 5; ++i){
    eur[i] = e5re[u*5+i]; eui[i] = e5im[u*5+i];
    evr[i] = e5re[v*5+i]; evi[i] = e5im[v*5+i];
  }
  float pr[25], pi[25];
  #pragma unroll
  for (int i = 0; i < 5; ++i)
    #pragma unroll
    for (int j = 0; j < 5; ++j){
      pr[i*5+j] = eur[i]*evr[j] - eui[i]*evi[j];
      pi[i*5+j] = eur[i]*evi[j] + eui[i]*evr[j];
    }
  float acc = 0.f;
  for (int f = 0; f < NF; ++f){
    const float* w = wn + (d*NF+f)*25;
    float gr = 0.f, gi = 0.f;
    #pragma unroll
    for (int k = 0; k < 25; ++k){ gr += w[k]*pr[k]; gi += w[k]*pi[k]; }
    acc += gr*gr + gi*gi;
  }
  Sarr[idx] = acc;
}

// ---------- denom, M = conj(otf)/denom ----------
__global__ __launch_bounds__(256) void denomM_k(const float* __restrict__ otfre, const float* __restrict__ otfim,
                                                const float* __restrict__ Sarr, const float* __restrict__ alpha,
                                                float* __restrict__ den, float* __restrict__ Mre, float* __restrict__ Mim){
  int idx = blockIdx.x*256 + threadIdx.x;
  if (idx >= ND*NN) return;
  int d = idx / NN, p = idx % NN;
  float orv = otfre[p], oiv = otfim[p];
  float B2 = orv*orv + oiv*oiv;
  float dv = B2 + expf(alpha[d]) * Sarr[idx];
  den[idx] = dv;
  Mre[idx] = orv / dv;
  Mim[idx] = -oiv / dv;
}

// ---------- cvar[d] = mean(B2/denom^2) ----------
__global__ void cvar_k(const float* __restrict__ otfre, const float* __restrict__ otfim,
                       const float* __restrict__ den, float* __restrict__ cvar){
  __shared__ float red[256];
  int d = blockIdx.x, tid = threadIdx.x;
  float acc = 0.f;
  for (int p = tid; p < NN; p += 256){
    float orv = otfre[p], oiv = otfim[p];
    float B2 = orv*orv + oiv*oiv;
    float dv = den[(size_t)d*NN + p];
    acc += B2 / (dv*dv);
  }
  red[tid] = acc; __syncthreads();
  for (int s = 128; s > 0; s >>= 1){
    if (tid < s) red[tid] += red[tid+s];
    __syncthreads();
  }
  if (tid == 0) cvar[d] = red[0] / (float)NN;
}

__global__ void cstdn_k(const float* __restrict__ stdn, const float* __restrict__ cvar,
                        float* __restrict__ out){
  int t = threadIdx.x;
  if (t >= NB*ND) return;
  int b = t >> 2, d = t & 3;
  float s = stdn[b];
  out[(size_t)NB*ND*NPIX + t] = sqrtf(s*s*cvar[d]);
}

// ---------- symmetric pad + pack pairs: z_p = xp_{2p} + i*xp_{2p+1} ----------
__global__ __launch_bounds__(256) void pad_k(const float* __restrict__ x,
                                             float* __restrict__ xpre, float* __restrict__ xpim){
  int idx = blockIdx.x*256 + threadIdx.x;
  if (idx >= NB*NN) return;
  int q = idx / NN, p = idx % NN;
  int i = p / NP, j = p % NP;
  int si = i - 4; if (si < 0) si = -si - 1; else if (si >= HH) si = 2*HH - 1 - si;
  int sj = j - 4; if (sj < 0) sj = -sj - 1; else if (sj >= HH) sj = 2*HH - 1 - sj;
  float v = x[(size_t)q*NPIX + (size_t)si*HH + sj];
  int pair = q >> 1;
  if (q & 1) xpim[(size_t)pair*NN + p] = v;
  else       xpre[(size_t)pair*NN + p] = v;
}

// ---------- edge-taper blend (applies independently to re/im planes) ----------
__global__ __launch_bounds__(256) void blend_k(float* __restrict__ xpre, float* __restrict__ xpim,
                                               const float* __restrict__ Bre, const float* __restrict__ Bim,
                                               const float* __restrict__ r_row, const float* __restrict__ r_col){
  int idx = blockIdx.x*256 + threadIdx.x;
  if (idx >= NB*NN) return;
  int q = idx / NN, p = idx % NN;
  int pair = q >> 1, isim = q & 1;
  int i = p / NP, j = p % NP;
  float br = 0.f, bc = 0.f;
  if (i < 9) br = r_row[i]; else if (i >= 511) br = r_row[519 - i];
  if (j < 9) bc = r_col[j]; else if (j >= 511) bc = r_col[519 - j];
  br /= r_row[0]; bc /= r_col[0];
  float t = (1.f - br) * (1.f - bc);
  size_t o = (size_t)pair*NN + p;
  if (isim) xpim[o] = t * xpim[o] + (1.f - t) * Bim[o];
  else      xpre[o] = t * xpre[o] + (1.f - t) * Bre[o];
}

// ---------- batched complex GEMM over 520x520 matrices ----------
// LEFT=1: C[b] = W * (X[b] masked);  LEFT=0: C[b] = X[b] * W
// OUTMODE=0: write complex to Ore/Oim.  OUTMODE=2: crop-write re->(2b,d), im->(2b+1,d).
// MASK=1: X element (r,c) is multiplied by MK[r*520+c] (complex) on load.
#define TM 64
#define TK 16
template<int LEFT, int OUTMODE, int MASK>
__global__ __launch_bounds__(256) void cgemm_k(
    const float* __restrict__ Wre, const float* __restrict__ Wim,
    const float* __restrict__ Xre, const float* __restrict__ Xim,
    const float* __restrict__ MKre, const float* __restrict__ MKim,
    float* __restrict__ Ore, float* __restrict__ Oim,
    float* __restrict__ crop_out, int dIdx)
{
  __shared__ float Asr[TM][TK+1], Asi[TM][TK+1];
  __shared__ float Bsr[TK][TM+1], Bsi[TK][TM+1];
  const int b = blockIdx.z;
  const size_t xoff = (size_t)b * NN;
  const int tx = threadIdx.x, ty = threadIdx.y;
  const int tid = ty*16 + tx;
  const int row0 = blockIdx.y*TM, col0 = blockIdx.x*TM;
  float crr[4][4] = {{0.f}}, cri[4][4] = {{0.f}};

  for (int k0 = 0; k0 < NP; k0 += TK){
    #pragma unroll
    for (int l = 0; l < 4; ++l){
      int e = tid + l*256;
      // A tile element
      int am = e >> 4, ak = e & 15;
      int gm = row0 + am, gk = k0 + ak;
      float vr = 0.f, vi = 0.f;
      if (gm < NP && gk < NP){
        if (LEFT){ vr = Wre[gm*NP+gk]; vi = Wim[gm*NP+gk]; }
        else {
          size_t ia = xoff + (size_t)gm*NP + gk;
          vr = Xre[ia]; vi = Xim[ia];
          if (MASK){
            float mr = MKre[gm*NP+gk], mi = MKim[gm*NP+gk];
            float t0 = vr*mr - vi*mi; vi = vr*mi + vi*mr; vr = t0;
          }
        }
      }
      Asr[am][ak] = vr; Asi[am][ak] = vi;
      // B tile element
      int bkr = e >> 6, bn = e & 63;
      int gk2 = k0 + bkr, gn = col0 + bn;
      vr = 0.f; vi = 0.f;
      if (gk2 < NP && gn < NP){
        if (LEFT){
          size_t ib = xoff + (size_t)gk2*NP + gn;
          vr = Xre[ib]; vi = Xim[ib];
          if (MASK){
            float mr = MKre[gk2*NP+gn], mi = MKim[gk2*NP+gn];
            float t0 = vr*mr - vi*mi; vi = vr*mi + vi*mr; vr = t0;
          }
        } else { vr = Wre[gk2*NP+gn]; vi = Wim[gk2*NP+gn]; }
      }
      Bsr[bkr][bn] = vr; Bsi[bkr][bn] = vi;
    }
    __syncthreads();
    #pragma unroll
    for (int kk = 0; kk < TK; ++kk){
      float ar[4], ai[4], br[4], bi[4];
      #pragma unroll
      for (int i = 0; i < 4; ++i){
        ar[i] = Asr[ty + i*16][kk]; ai[i] = Asi[ty + i*16][kk];
        br[i] = Bsr[kk][tx + i*16]; bi[i] = Bsi[kk][tx + i*16];
      }
      #pragma unroll
      for (int i = 0; i < 4; ++i)
        #pragma unroll
        for (int j = 0; j < 4; ++j){
          crr[i][j] += ar[i]*br[j] - ai[i]*bi[j];
          cri[i][j] += ar[i]*bi[j] + ai[i]*br[j];
        }
    }
    __syncthreads();
  }

  #pragma unroll
  for (int i = 0; i < 4; ++i){
    int m = row0 + ty + i*16;
    if (m >= NP) continue;
    #pragma unroll
    for (int j = 0; j < 4; ++j){
      int n = col0 + tx + j*16;
      if (n >= NP) continue;
      if (OUTMODE == 0){
        Ore[xoff + (size_t)m*NP + n] = crr[i][j];
        Oim[xoff + (size_t)m*NP + n] = cri[i][j];
      } else {
        if (m >= 4 && m < 516 && n >= 4 && n < 516){
          size_t px = (size_t)(m-4)*HH + (n-4);
          crop_out[((size_t)((2*b  )*ND + dIdx))*NPIX + px] = crr[i][j];
          crop_out[((size_t)((2*b+1)*ND + dIdx))*NPIX + px] = cri[i][j];
        }
      }
    }
  }
}

extern "C" void kernel_launch(void* const* d_in, const int* in_sizes, int n_in,
                              void* d_out, int out_size, void* d_ws, size_t ws_size,
                              hipStream_t stream){
  const float* x     = (const float*)d_in[0];
  const float* bk    = (const float*)d_in[1];
  const float* stdn  = (const float*)d_in[2];
  const float* cw    = (const float*)d_in[3];
  const float* scale = (const float*)d_in[4];
  const float* alpha = (const float*)d_in[5];
  float* out = (float*)d_out;
  float* ws  = (float*)d_ws;

  size_t off = 0;
  auto alloc = [&](size_t n){ float* p = ws + off; off += n; return p; };
  float* Wfre = alloc(NN); float* Wfim = alloc(NN);
  float* Wire = alloc(NN); float* Wiim = alloc(NN);
  float* otfre = alloc(NN); float* otfim = alloc(NN);
  float* Sarr = alloc((size_t)ND*NN);
  float* den  = alloc((size_t)ND*NN);
  float* Mre  = alloc((size_t)ND*NN);
  float* Mim  = alloc((size_t)ND*NN);
  float* xpre = alloc((size_t)NPAIR*NN); float* xpim = alloc((size_t)NPAIR*NN);
  float* Are  = alloc((size_t)NPAIR*NN); float* Aim  = alloc((size_t)NPAIR*NN);
  float* Bre  = alloc((size_t)NPAIR*NN); float* Bim  = alloc((size_t)NPAIR*NN);
  float* e5re = alloc(NP*5); float* e5im = alloc(NP*5);
  float* r_row = alloc(16); float* r_col = alloc(16);
  float* wn   = alloc(ND*NF*25);
  float* cvar = alloc(4);
  if (ws_size < off * sizeof(float)) return;  // insufficient workspace

  // setup
  build_W_k  <<<(NN+255)/256, 256, 0, stream>>>(Wfre, Wfim, Wire, Wiim);
  build_e5_k <<<(NP*5+255)/256, 256, 0, stream>>>(e5re, e5im);
  build_otf_k<<<(NN+255)/256, 256, 0, stream>>>(bk, otfre, otfim);
  taper_r_k  <<<1, 32, 0, stream>>>(bk, r_row, r_col);
  norm_w_k   <<<1, 128, 0, stream>>>(cw, scale, wn);
  S_k        <<<(ND*NN+255)/256, 256, 0, stream>>>(wn, e5re, e5im, Sarr);
  denomM_k   <<<(ND*NN+255)/256, 256, 0, stream>>>(otfre, otfim, Sarr, alpha, den, Mre, Mim);
  cvar_k     <<<ND, 256, 0, stream>>>(otfre, otfim, den, cvar);
  cstdn_k    <<<1, 64, 0, stream>>>(stdn, cvar, out);
  pad_k      <<<(NB*NN+255)/256, 256, 0, stream>>>(x, xpre, xpim);

  dim3 gg((NP+TM-1)/TM, (NP+TM-1)/TM, NPAIR);
  dim3 bb(16, 16);

  // fft2(xp): A = Wf*z ; B = A*Wf
  cgemm_k<1,0,0><<<gg, bb, 0, stream>>>(Wfre, Wfim, xpre, xpim, nullptr, nullptr, Are, Aim, nullptr, 0);
  cgemm_k<0,0,0><<<gg, bb, 0, stream>>>(Wfre, Wfim, Are, Aim, nullptr, nullptr, Bre, Bim, nullptr, 0);
  // blurred = ifft2(Xhat .* otf): A = Wi*(B.*otf) ; B = A*Wi
  cgemm_k<1,0,1><<<gg, bb, 0, stream>>>(Wire, Wiim, Bre, Bim, otfre, otfim, Are, Aim, nullptr, 0);
  cgemm_k<0,0,0><<<gg, bb, 0, stream>>>(Wire, Wiim, Are, Aim, nullptr, nullptr, Bre, Bim, nullptr, 0);
  // xp = taper*xp + (1-taper)*blurred
  blend_k<<<(NB*NN+255)/256, 256, 0, stream>>>(xpre, xpim, Bre, Bim, r_row, r_col);
  // fft2(xp2)
  cgemm_k<1,0,0><<<gg, bb, 0, stream>>>(Wfre, Wfim, xpre, xpim, nullptr, nullptr, Are, Aim, nullptr, 0);
  cgemm_k<0,0,0><<<gg, bb, 0, stream>>>(Wfre, Wfim, Are, Aim, nullptr, nullptr, Bre, Bim, nullptr, 0);
  // per wiener level: out_{b,d} = Re/Im of ifft2(Xhat2 .* M_d), cropped
  for (int d = 0; d < ND; ++d){
    cgemm_k<1,0,1><<<gg, bb, 0, stream>>>(Wire, Wiim, Bre, Bim, Mre + (size_t)d*NN, Mim + (size_t)d*NN, Are, Aim, nullptr, 0);
    cgemm_k<0,2,0><<<gg, bb, 0, stream>>>(Wire, Wiim, Are, Aim, nullptr, nullptr, nullptr, nullptr, out, d);
  }
}

// Round 2
// 1250.628 us; speedup vs baseline: 6.4939x; 6.4939x over previous
//
#include <hip/hip_runtime.h>
#include <math.h>

#define NP    520
#define NN    (520*520)
#define HH    512
#define NPIX  (512*512)
#define NB    16
#define NPAIR 8
#define ND    4
#define NF    24
#define KS    544               // padded row stride (elements)
#define RS    576               // padded row count
#define PLANE ((size_t)RS*KS)   // 313344 elements per plane
#define S8P   (8*PLANE)         // batched plane stride
#define TWO_PI 6.283185307179586f

typedef unsigned short u16;
typedef __attribute__((ext_vector_type(8))) short bf16x8;
typedef __attribute__((ext_vector_type(4))) float f32x4;

__device__ __forceinline__ u16 f2bf(float f){
  unsigned u = __float_as_uint(f);
  u += 0x7FFFu + ((u >> 16) & 1u);
  return (u16)(u >> 16);
}
__device__ __forceinline__ void split2(float f, u16& hi, u16& lo){
  hi = f2bf(f);
  float fh = __uint_as_float(((unsigned)hi) << 16);
  lo = f2bf(f - fh);
}
__device__ __forceinline__ float rec(u16 h, u16 l){
  return __uint_as_float(((unsigned)h) << 16) + __uint_as_float(((unsigned)l) << 16);
}
__device__ __forceinline__ void gll16(const u16* g, u16* l){
  __builtin_amdgcn_global_load_lds(
      (const __attribute__((address_space(1))) void*)g,
      (__attribute__((address_space(3))) void*)l, 16, 0, 0);
}
#define MF(a,b,c) __builtin_amdgcn_mfma_f32_16x16x32_bf16((a),(b),(c),0,0,0)

// ================= setup kernels =================

// W pair arrays: planes {rehi, relo, imhi, imlo}, padded region = 0
__global__ __launch_bounds__(256) void build_Wpair_k(u16* __restrict__ wf, u16* __restrict__ wi){
  int idx = blockIdx.x*256 + threadIdx.x;
  if (idx >= (int)PLANE) return;
  int r = idx / KS, k = idx % KS;
  float fr=0.f, fi=0.f, ir=0.f, ii=0.f;
  if (r < NP && k < NP){
    int m = (int)(((long long)r * (long long)k) % NP);
    float ang = TWO_PI * (float)m / (float)NP;
    float s, c; sincosf(ang, &s, &c);
    fr = c; fi = -s;
    ir = c * (1.0f/NP); ii = s * (1.0f/NP);
  }
  u16 h, lo;
  split2(fr,h,lo); wf[0*PLANE+idx]=h; wf[1*PLANE+idx]=lo;
  split2(fi,h,lo); wf[2*PLANE+idx]=h; wf[3*PLANE+idx]=lo;
  split2(ir,h,lo); wi[0*PLANE+idx]=h; wi[1*PLANE+idx]=lo;
  split2(ii,h,lo); wi[2*PLANE+idx]=h; wi[3*PLANE+idx]=lo;
}

__global__ __launch_bounds__(256) void build_e5_k(float* __restrict__ e5re, float* __restrict__ e5im){
  int idx = blockIdx.x*256 + threadIdx.x;
  if (idx >= NP*5) return;
  int u = idx / 5, i = idx % 5;
  int t = (u*(i-2)) % NP; if (t < 0) t += NP;
  float ang = TWO_PI * (float)t / (float)NP;
  float s, c; sincosf(ang, &s, &c);
  e5re[idx] = c; e5im[idx] = -s;
}

// transposed blur OTF: otfT[r*NP+c] = otf(c, r)
__global__ __launch_bounds__(256) void build_otfT_k(const float* __restrict__ bk,
                                                    float* __restrict__ otre, float* __restrict__ otim){
  int idx = blockIdx.x*256 + threadIdx.x;
  if (idx >= NN) return;
  int u = idx % NP, v = idx / NP;   // swapped -> transposed
  float ar = 0.f, ai = 0.f;
  for (int i = 0; i < 9; ++i)
    for (int j = 0; j < 9; ++j){
      int t = (u*(i-4) + v*(j-4)) % NP; if (t < 0) t += NP;
      float ang = TWO_PI * (float)t / (float)NP;
      float s, c; sincosf(ang, &s, &c);
      float w = bk[i*9+j];
      ar += w * c; ai -= w * s;
    }
  otre[idx] = ar; otim[idx] = ai;
}

__global__ void taper_r_k(const float* __restrict__ bk, float* __restrict__ r_row, float* __restrict__ r_col){
  int t = threadIdx.x;
  if (t >= 18) return;
  int k = t % 9;
  bool rowp = (t < 9);
  float proj[9];
  for (int m = 0; m < 9; ++m){
    float a = 0.f;
    for (int j = 0; j < 9; ++j) a += rowp ? bk[m*9+j] : bk[j*9+m];
    proj[m] = a;
  }
  float acc = 0.f;
  for (int m = 0; m + k < 9; ++m) acc += proj[m] * proj[m+k];
  (rowp ? r_row : r_col)[k] = acc;
}

__global__ void norm_w_k(const float* __restrict__ cw, const float* __restrict__ scale,
                         float* __restrict__ wn){
  int idx = blockIdx.x*blockDim.x + threadIdx.x;
  if (idx >= ND*NF) return;
  const float* wp = cw + idx*25;
  float mean = 0.f;
  for (int k = 0; k < 25; ++k) mean += wp[k];
  mean *= (1.0f/25.0f);
  float ss = 0.f;
  for (int k = 0; k < 25; ++k){ float d = wp[k]-mean; ss += d*d; }
  float sc = scale[idx] / sqrtf(ss);
  for (int k = 0; k < 25; ++k) wn[idx*25+k] = (wp[k]-mean)*sc;
}

// transposed S: ST[d][r*NP+c] = S_d(c, r)
__global__ __launch_bounds__(256) void S_k(const float* __restrict__ wn,
                                           const float* __restrict__ e5re, const float* __restrict__ e5im,
                                           float* __restrict__ Sarr){
  int idx = blockIdx.x*256 + threadIdx.x;
  if (idx >= ND*NN) return;
  int d = idx / NN, p = idx % NN;
  int u = p % NP, v = p / NP;  // swapped
  float eur[5], eui[5], evr[5], evi[5];
  #pragma unroll
  for (int i = 0; i < 5; ++i){
    eur[i] = e5re[u*5+i]; eui[i] = e5im[u*5+i];
    evr[i] = e5re[v*5+i]; evi[i] = e5im[v*5+i];
  }
  float pr[25], pi[25];
  #pragma unroll
  for (int i = 0; i < 5; ++i)
    #pragma unroll
    for (int j = 0; j < 5; ++j){
      pr[i*5+j] = eur[i]*evr[j] - eui[i]*evi[j];
      pi[i*5+j] = eur[i]*evi[j] + eui[i]*evr[j];
    }
  float acc = 0.f;
  for (int f = 0; f < NF; ++f){
    const float* w = wn + (d*NF+f)*25;
    float gr = 0.f, gi = 0.f;
    #pragma unroll
    for (int k = 0; k < 25; ++k){ gr += w[k]*pr[k]; gi += w[k]*pi[k]; }
    acc += gr*gr + gi*gi;
  }
  Sarr[idx] = acc;
}

// transposed wiener masks MT_d = conj(otfT)/denT
__global__ __launch_bounds__(256) void denomMT_k(const float* __restrict__ otre, const float* __restrict__ otim,
                                                 const float* __restrict__ Sarr, const float* __restrict__ alpha,
                                                 float* __restrict__ MTre, float* __restrict__ MTim){
  int idx = blockIdx.x*256 + threadIdx.x;
  if (idx >= ND*NN) return;
  int d = idx / NN, p = idx % NN;
  float orv = otre[p], oiv = otim[p];
  float B2 = orv*orv + oiv*oiv;
  float dv = B2 + expf(alpha[d]) * Sarr[idx];
  MTre[idx] = orv / dv;
  MTim[idx] = -oiv / dv;
}

__global__ void cvar_k(const float* __restrict__ otre, const float* __restrict__ otim,
                       const float* __restrict__ Sarr, const float* __restrict__ alpha,
                       float* __restrict__ cvar){
  __shared__ float red[256];
  int d = blockIdx.x, tid = threadIdx.x;
  float a = expf(alpha[d]);
  float acc = 0.f;
  for (int p = tid; p < NN; p += 256){
    float orv = otre[p], oiv = otim[p];
    float B2 = orv*orv + oiv*oiv;
    float dv = B2 + a * Sarr[(size_t)d*NN + p];
    acc += B2 / (dv*dv);
  }
  red[tid] = acc; __syncthreads();
  for (int s = 128; s > 0; s >>= 1){
    if (tid < s) red[tid] += red[tid+s];
    __syncthreads();
  }
  if (tid == 0) cvar[d] = red[0] / (float)NN;
}

__global__ void cstdn_k(const float* __restrict__ stdn, const float* __restrict__ cvar,
                        float* __restrict__ out){
  int t = threadIdx.x;
  if (t >= NB*ND) return;
  int b = t >> 2, d = t & 3;
  float s = stdn[b];
  out[(size_t)NB*ND*NPIX + t] = sqrtf(s*s*cvar[d]);
}

// ================= pointwise pair kernels =================

// symmetric pad, pack pairs, store TRANSPOSED as bf16 hi/lo pairs into slab
__global__ __launch_bounds__(256) void pad_pair_k(const float* __restrict__ x, u16* __restrict__ MA){
  int idx = blockIdx.x*256 + threadIdx.x;
  if (idx >= NB*NN) return;
  int q = idx / NN, p = idx % NN;
  int r = p / NP, c = p % NP;       // transposed coords
  int i = c - 4; i = (i < 0) ? (-i-1) : ((i >= HH) ? (2*HH-1-i) : i);
  int j = r - 4; j = (j < 0) ? (-j-1) : ((j >= HH) ? (2*HH-1-j) : j);
  float v = x[(size_t)q*NPIX + (size_t)i*HH + j];
  int pair = q >> 1, im = q & 1;
  u16 h, lo; split2(v, h, lo);
  size_t o = (size_t)pair*PLANE + (size_t)r*KS + c;
  MA[(size_t)(im*2+0)*S8P + o] = h;
  MA[(size_t)(im*2+1)*S8P + o] = lo;
}

// xp2T = taperT*xpT + (1-taperT)*blurT
__global__ __launch_bounds__(256) void blend_pair_k(const u16* __restrict__ MA, const u16* __restrict__ MB,
                                                    u16* __restrict__ MC,
                                                    const float* __restrict__ r_row, const float* __restrict__ r_col){
  int idx = blockIdx.x*256 + threadIdx.x;
  if (idx >= NB*NN) return;
  int q = idx / NN, p = idx % NN;
  int r = p / NP, c = p % NP;
  int pair = q >> 1, im = q & 1;
  size_t o = (size_t)pair*PLANE + (size_t)r*KS + c;
  float xv = rec(MA[(size_t)(im*2)*S8P + o], MA[(size_t)(im*2+1)*S8P + o]);
  float bv = rec(MB[(size_t)(im*2)*S8P + o], MB[(size_t)(im*2+1)*S8P + o]);
  int i = c, j = r;   // original (row, col) of xp
  float brv = (i < 9) ? r_row[i] : ((i >= 511) ? r_row[519-i] : 0.f);
  float bcv = (j < 9) ? r_col[j] : ((j >= 511) ? r_col[519-j] : 0.f);
  brv /= r_row[0]; bcv /= r_col[0];
  float t = (1.f - brv) * (1.f - bcv);
  float v = t*xv + (1.f - t)*bv;
  u16 h, lo; split2(v, h, lo);
  MC[(size_t)(im*2+0)*S8P + o] = h;
  MC[(size_t)(im*2+1)*S8P + o] = lo;
}

// OUT = IN .* mask (complex, mask f32 per-element), both bf16-pair slabs
__global__ __launch_bounds__(256) void maskT_k(const u16* __restrict__ IN, u16* __restrict__ OUT,
                                               const float* __restrict__ Mre, const float* __restrict__ Mim){
  int idx = blockIdx.x*256 + threadIdx.x;
  if (idx >= NPAIR*NN) return;
  int pr = idx / NN, p = idx % NN;
  int r = p / NP, c = p % NP;
  size_t o = (size_t)pr*PLANE + (size_t)r*KS + c;
  float vr = rec(IN[0*S8P + o], IN[1*S8P + o]);
  float vi = rec(IN[2*S8P + o], IN[3*S8P + o]);
  float mr = Mre[p], mi = Mim[p];
  float wr = vr*mr - vi*mi;
  float wi = vr*mi + vi*mr;
  u16 h, lo;
  split2(wr,h,lo); OUT[0*S8P+o]=h; OUT[1*S8P+o]=lo;
  split2(wi,h,lo); OUT[2*S8P+o]=h; OUT[3*S8P+o]=lo;
}

// ================= MFMA complex GEMM: OUT(m,n) = sum_k P(m,k) * Qtile[n][k] =================
// P,Q: bf16 pair slabs (planes {rehi,relo,imhi,imlo}); W is symmetric so Q=W gives OUT=P*W.
// CROP=0: write bf16-pair slab O.  CROP=1: write real->out[2b][d], imag->out[2b+1][d], cropped.
template<int CROP>
__global__ __launch_bounds__(256) void gemm_k(
    const u16* __restrict__ P, size_t pPlane, size_t pPair,
    const u16* __restrict__ Q, size_t qPlane, size_t qPair,
    u16* __restrict__ O, float* __restrict__ cropOut, int dIdx)
{
  __shared__ u16 lds[8*2048];   // 8 planes x [64 rows][32 k] bf16 (P:0-3, Q:4-7)
  const int tid = threadIdx.x;
  const int l = tid & 63, w = tid >> 6;
  const int b = blockIdx.z;
  const int R0 = blockIdx.y * 64, C0 = blockIdx.x * 64;

  // staging geometry: lane stages 16B chunk; XOR-swizzled source so reads are conflict-free
  const int rt = w*16 + (l >> 2);
  const int csrc = (l & 3) ^ ((rt >> 1) & 3);
  const size_t pOff = (size_t)b*pPair + (size_t)(R0+rt)*KS + (size_t)(csrc*8);
  const size_t qOff = (size_t)b*qPair + (size_t)(C0+rt)*KS + (size_t)(csrc*8);
  u16* ldsW = lds + w*512;

  const int lm = l & 15, lc = l >> 4;
  const int wm = w >> 1, wn = w & 1;

  f32x4 zero4 = {0.f, 0.f, 0.f, 0.f};
  f32x4 aRe[2][2], aIm[2][2];
  #pragma unroll
  for (int i = 0; i < 2; ++i)
    #pragma unroll
    for (int j = 0; j < 2; ++j){ aRe[i][j] = zero4; aIm[i][j] = zero4; }

  #pragma unroll 1
  for (int k0 = 0; k0 < KS; k0 += 32){
    #pragma unroll
    for (int p = 0; p < 4; ++p){
      gll16(P + (size_t)p*pPlane + pOff + k0, ldsW + p*2048);
      gll16(Q + (size_t)p*qPlane + qOff + k0, ldsW + (4+p)*2048);
    }
    __syncthreads();

    bf16x8 pf[2][4], qf[2][4];
    #pragma unroll
    for (int mi = 0; mi < 2; ++mi){
      int r = wm*32 + mi*16 + lm;
      int co = ((lc ^ ((r >> 1) & 3)) << 3);
      #pragma unroll
      for (int p = 0; p < 4; ++p)
        pf[mi][p] = *(const bf16x8*)(lds + p*2048 + r*32 + co);
    }
    #pragma unroll
    for (int ni = 0; ni < 2; ++ni){
      int r = wn*32 + ni*16 + lm;
      int co = ((lc ^ ((r >> 1) & 3)) << 3);
      #pragma unroll
      for (int p = 0; p < 4; ++p)
        qf[ni][p] = *(const bf16x8*)(lds + (4+p)*2048 + r*32 + co);
    }

    #pragma unroll
    for (int ni = 0; ni < 2; ++ni){
      bf16x8 nih = qf[ni][2] ^ (short)0x8000;   // -im_hi
      bf16x8 nil = qf[ni][3] ^ (short)0x8000;   // -im_lo
      #pragma unroll
      for (int mi = 0; mi < 2; ++mi){
        f32x4 r = aRe[mi][ni], im = aIm[mi][ni];
        r = MF(pf[mi][0], qf[ni][0], r);    // re*re (hi*hi, hi*lo, lo*hi)
        r = MF(pf[mi][0], qf[ni][1], r);
        r = MF(pf[mi][1], qf[ni][0], r);
        r = MF(pf[mi][2], nih, r);          // -im*im
        r = MF(pf[mi][2], nil, r);
        r = MF(pf[mi][3], nih, r);
        im = MF(pf[mi][0], qf[ni][2], im);  // re*im
        im = MF(pf[mi][0], qf[ni][3], im);
        im = MF(pf[mi][1], qf[ni][2], im);
        im = MF(pf[mi][2], qf[ni][0], im);  // im*re
        im = MF(pf[mi][2], qf[ni][1], im);
        im = MF(pf[mi][3], qf[ni][0], im);
        aRe[mi][ni] = r; aIm[mi][ni] = im;
      }
    }
    __syncthreads();
  }

  // epilogue
  #pragma unroll
  for (int mi = 0; mi < 2; ++mi)
    #pragma unroll
    for (int ni = 0; ni < 2; ++ni){
      int cb = C0 + wn*32 + ni*16 + lm;
      int rb = R0 + wm*32 + mi*16 + lc*4;
      #pragma unroll
      for (int e = 0; e < 4; ++e){
        int rr = rb + e;
        float vr = aRe[mi][ni][e], vi = aIm[mi][ni][e];
        if (CROP){
          if (rr >= 4 && rr < 516 && cb >= 4 && cb < 516){
            size_t px = (size_t)(rr-4)*HH + (cb-4);
            cropOut[((size_t)(2*b  )*ND + dIdx)*NPIX + px] = vr;
            cropOut[((size_t)(2*b+1)*ND + dIdx)*NPIX + px] = vi;
          }
        } else {
          if (rr < NP && cb < NP){
            size_t o = (size_t)b*PLANE + (size_t)rr*KS + cb;
            u16 h, lo;
            split2(vr, h, lo); O[0*S8P+o] = h; O[1*S8P+o] = lo;
            split2(vi, h, lo); O[2*S8P+o] = h; O[3*S8P+o] = lo;
          }
        }
      }
    }
}

// ================= host =================

extern "C" void kernel_launch(void* const* d_in, const int* in_sizes, int n_in,
                              void* d_out, int out_size, void* d_ws, size_t ws_size,
                              hipStream_t stream){
  const float* x     = (const float*)d_in[0];
  const float* bk    = (const float*)d_in[1];
  const float* stdn  = (const float*)d_in[2];
  const float* cw    = (const float*)d_in[3];
  const float* scale = (const float*)d_in[4];
  const float* alpha = (const float*)d_in[5];
  float* out = (float*)d_out;

  char* base = (char*)d_ws;
  size_t off = 0;
  auto alloc = [&](size_t bytes)->void*{
    void* p = base + off;
    off += (bytes + 255) & ~(size_t)255;
    return p;
  };
  u16* MA = (u16*)alloc(4*S8P*sizeof(u16));
  u16* MB = (u16*)alloc(4*S8P*sizeof(u16));
  u16* MC = (u16*)alloc(4*S8P*sizeof(u16));
  u16* WF = (u16*)alloc(4*PLANE*sizeof(u16));
  u16* WI = (u16*)alloc(4*PLANE*sizeof(u16));
  size_t zeroBytes = off;   // slabs + W get memset to 0 (padded regions must be 0)
  float* otre = (float*)alloc(NN*4);
  float* otim = (float*)alloc(NN*4);
  float* ST   = (float*)alloc((size_t)ND*NN*4);
  float* MTre = (float*)alloc((size_t)ND*NN*4);
  float* MTim = (float*)alloc((size_t)ND*NN*4);
  float* e5re = (float*)alloc(NP*5*4);
  float* e5im = (float*)alloc(NP*5*4);
  float* r_row = (float*)alloc(64);
  float* r_col = (float*)alloc(64);
  float* wn   = (float*)alloc(ND*NF*25*4);
  float* cvar = (float*)alloc(64);
  if (off > ws_size) return;  // insufficient workspace

  hipMemsetAsync(d_ws, 0, zeroBytes, stream);

  build_Wpair_k<<<((int)PLANE+255)/256, 256, 0, stream>>>(WF, WI);
  build_e5_k   <<<(NP*5+255)/256, 256, 0, stream>>>(e5re, e5im);
  build_otfT_k <<<(NN+255)/256, 256, 0, stream>>>(bk, otre, otim);
  taper_r_k    <<<1, 32, 0, stream>>>(bk, r_row, r_col);
  norm_w_k     <<<1, 128, 0, stream>>>(cw, scale, wn);
  S_k          <<<(ND*NN+255)/256, 256, 0, stream>>>(wn, e5re, e5im, ST);
  denomMT_k    <<<(ND*NN+255)/256, 256, 0, stream>>>(otre, otim, ST, alpha, MTre, MTim);
  cvar_k       <<<ND, 256, 0, stream>>>(otre, otim, ST, alpha, cvar);
  cstdn_k      <<<1, 64, 0, stream>>>(stdn, cvar, out);
  pad_pair_k   <<<(NB*NN+255)/256, 256, 0, stream>>>(x, MA);   // xpT

  dim3 gg(9, 9, NPAIR);
  const size_t BP = S8P, BW = PLANE;   // plane strides: batched slab / W
  // G1: C1 = W*xp           (P=Wf, Q=xpT)     -> MB
  gemm_k<0><<<gg,256,0,stream>>>(WF,BW,0, MA,BP,PLANE, MB, nullptr, 0);
  // G2: F1^T                (P=Wf, Q=C1)      -> MC
  gemm_k<0><<<gg,256,0,stream>>>(WF,BW,0, MB,BP,PLANE, MC, nullptr, 0);
  // A3 = F1^T .* otfT       -> MB
  maskT_k<<<(NPAIR*NN+255)/256, 256, 0, stream>>>(MC, MB, otre, otim);
  // G3: C3 = Wi*blurF       (P=Wi, Q=A3)      -> MC
  gemm_k<0><<<gg,256,0,stream>>>(WI,BW,0, MB,BP,PLANE, MC, nullptr, 0);
  // G4: blur^T              (P=Wi, Q=C3)      -> MB
  gemm_k<0><<<gg,256,0,stream>>>(WI,BW,0, MC,BP,PLANE, MB, nullptr, 0);
  // blend: xp2T = taperT*xpT + (1-taperT)*blurT  -> MC
  blend_pair_k<<<(NB*NN+255)/256, 256, 0, stream>>>(MA, MB, MC, r_row, r_col);
  // G5: C5 = W*xp2          (P=Wf, Q=xp2T)    -> MA
  gemm_k<0><<<gg,256,0,stream>>>(WF,BW,0, MC,BP,PLANE, MA, nullptr, 0);
  // G6: F2^T                (P=Wf, Q=C5)      -> MB
  gemm_k<0><<<gg,256,0,stream>>>(WF,BW,0, MA,BP,PLANE, MB, nullptr, 0);
  for (int d = 0; d < ND; ++d){
    // A7 = F2^T .* MT_d     -> MC
    maskT_k<<<(NPAIR*NN+255)/256, 256, 0, stream>>>(MB, MC, MTre + (size_t)d*NN, MTim + (size_t)d*NN);
    // G7: C7 = Wi*Xf_d      (P=Wi, Q=A7)      -> MA
    gemm_k<0><<<gg,256,0,stream>>>(WI,BW,0, MC,BP,PLANE, MA, nullptr, 0);
    // G8: out_d = C7*Wi (crop) (P=C7, Q=Wi)
    gemm_k<1><<<gg,256,0,stream>>>(MA,BP,PLANE, WI,BW,0, nullptr, out, d);
  }
}

// Round 3
// 810.651 us; speedup vs baseline: 10.0184x; 1.5427x over previous
//
#include <hip/hip_runtime.h>
#include <math.h>

#define NP    520
#define NN    (520*520)
#define HH    512
#define NPIX  (512*512)
#define NB    16
#define NPAIR 8
#define ND    4
#define NF    24
#define KS    544               // padded row stride (elements)
#define RS    576               // padded row count
#define PLANE ((size_t)RS*KS)   // 313344 elements per plane
#define S8P   (8*PLANE)         // batched plane stride
#define TWO_PI 6.283185307179586f

typedef unsigned short u16;
typedef __attribute__((ext_vector_type(8))) short bf16x8;
typedef __attribute__((ext_vector_type(4))) float f32x4;

__device__ __forceinline__ int wrap520(int t){ t %= NP; return t < 0 ? t + NP : t; }

__device__ __forceinline__ u16 f2bf(float f){
  unsigned u = __float_as_uint(f);
  u += 0x7FFFu + ((u >> 16) & 1u);
  return (u16)(u >> 16);
}
__device__ __forceinline__ void split2(float f, u16& hi, u16& lo){
  hi = f2bf(f);
  float fh = __uint_as_float(((unsigned)hi) << 16);
  lo = f2bf(f - fh);
}
__device__ __forceinline__ float rec(u16 h, u16 l){
  return __uint_as_float(((unsigned)h) << 16) + __uint_as_float(((unsigned)l) << 16);
}
__device__ __forceinline__ void gll16(const u16* g, u16* l){
  __builtin_amdgcn_global_load_lds(
      (const __attribute__((address_space(1))) void*)g,
      (__attribute__((address_space(3))) void*)l, 16, 0, 0);
}
#define MF(a,b,c) __builtin_amdgcn_mfma_f32_16x16x32_bf16((a),(b),(c),0,0,0)

// ================= setup kernels =================

// W pair arrays: planes {rehi, relo, imhi, imlo}, padded region = 0
__global__ __launch_bounds__(256) void build_Wpair_k(u16* __restrict__ wf, u16* __restrict__ wi){
  int idx = blockIdx.x*256 + threadIdx.x;
  if (idx >= (int)PLANE) return;
  int r = idx / KS, k = idx % KS;
  float fr=0.f, fi=0.f, ir=0.f, ii=0.f;
  if (r < NP && k < NP){
    int m = (int)(((long long)r * (long long)k) % NP);
    float ang = TWO_PI * (float)m / (float)NP;
    float s, c; sincosf(ang, &s, &c);
    fr = c; fi = -s;
    ir = c * (1.0f/NP); ii = s * (1.0f/NP);
  }
  u16 h, lo;
  split2(fr,h,lo); wf[0*PLANE+idx]=h; wf[1*PLANE+idx]=lo;
  split2(fi,h,lo); wf[2*PLANE+idx]=h; wf[3*PLANE+idx]=lo;
  split2(ir,h,lo); wi[0*PLANE+idx]=h; wi[1*PLANE+idx]=lo;
  split2(ii,h,lo); wi[2*PLANE+idx]=h; wi[3*PLANE+idx]=lo;
}

__global__ __launch_bounds__(256) void build_e5_k(float* __restrict__ e5re, float* __restrict__ e5im){
  int idx = blockIdx.x*256 + threadIdx.x;
  if (idx >= NP*5) return;
  int u = idx / 5, i = idx % 5;
  int t = (u*(i-2)) % NP; if (t < 0) t += NP;
  float ang = TWO_PI * (float)t / (float)NP;
  float s, c; sincosf(ang, &s, &c);
  e5re[idx] = c; e5im[idx] = -s;
}

// transposed blur OTF: otfT[r*NP+c] = otf(c, r)
__global__ __launch_bounds__(256) void build_otfT_k(const float* __restrict__ bk,
                                                    float* __restrict__ otre, float* __restrict__ otim){
  int idx = blockIdx.x*256 + threadIdx.x;
  if (idx >= NN) return;
  int u = idx % NP, v = idx / NP;   // swapped -> transposed
  float ar = 0.f, ai = 0.f;
  for (int i = 0; i < 9; ++i)
    for (int j = 0; j < 9; ++j){
      int t = (u*(i-4) + v*(j-4)) % NP; if (t < 0) t += NP;
      float ang = TWO_PI * (float)t / (float)NP;
      float s, c; sincosf(ang, &s, &c);
      float w = bk[i*9+j];
      ar += w * c; ai -= w * s;
    }
  otre[idx] = ar; otim[idx] = ai;
}

__global__ void taper_r_k(const float* __restrict__ bk, float* __restrict__ r_row, float* __restrict__ r_col){
  int t = threadIdx.x;
  if (t >= 18) return;
  int k = t % 9;
  bool rowp = (t < 9);
  float proj[9];
  for (int m = 0; m < 9; ++m){
    float a = 0.f;
    for (int j = 0; j < 9; ++j) a += rowp ? bk[m*9+j] : bk[j*9+m];
    proj[m] = a;
  }
  float acc = 0.f;
  for (int m = 0; m + k < 9; ++m) acc += proj[m] * proj[m+k];
  (rowp ? r_row : r_col)[k] = acc;
}

__global__ void norm_w_k(const float* __restrict__ cw, const float* __restrict__ scale,
                         float* __restrict__ wn){
  int idx = blockIdx.x*blockDim.x + threadIdx.x;
  if (idx >= ND*NF) return;
  const float* wp = cw + idx*25;
  float mean = 0.f;
  for (int k = 0; k < 25; ++k) mean += wp[k];
  mean *= (1.0f/25.0f);
  float ss = 0.f;
  for (int k = 0; k < 25; ++k){ float d = wp[k]-mean; ss += d*d; }
  float sc = scale[idx] / sqrtf(ss);
  for (int k = 0; k < 25; ++k) wn[idx*25+k] = (wp[k]-mean)*sc;
}

// transposed S: ST[d][r*NP+c] = S_d(c, r)
__global__ __launch_bounds__(256) void S_k(const float* __restrict__ wn,
                                           const float* __restrict__ e5re, const float* __restrict__ e5im,
                                           float* __restrict__ Sarr){
  int idx = blockIdx.x*256 + threadIdx.x;
  if (idx >= ND*NN) return;
  int d = idx / NN, p = idx % NN;
  int u = p % NP, v = p / NP;  // swapped
  float eur[5], eui[5], evr[5], evi[5];
  #pragma unroll
  for (int i = 0; i < 5; ++i){
    eur[i] = e5re[u*5+i]; eui[i] = e5im[u*5+i];
    evr[i] = e5re[v*5+i]; evi[i] = e5im[v*5+i];
  }
  float pr[25], pi[25];
  #pragma unroll
  for (int i = 0; i < 5; ++i)
    #pragma unroll
    for (int j = 0; j < 5; ++j){
      pr[i*5+j] = eur[i]*evr[j] - eui[i]*evi[j];
      pi[i*5+j] = eur[i]*evi[j] + eui[i]*evr[j];
    }
  float acc = 0.f;
  for (int f = 0; f < NF; ++f){
    const float* w = wn + (d*NF+f)*25;
    float gr = 0.f, gi = 0.f;
    #pragma unroll
    for (int k = 0; k < 25; ++k){ gr += w[k]*pr[k]; gi += w[k]*pi[k]; }
    acc += gr*gr + gi*gi;
  }
  Sarr[idx] = acc;
}

// transposed wiener masks MT_d = conj(otfT)/denT, fused cvar partial reduction
__global__ __launch_bounds__(256) void denomMTcvar_k(
    const float* __restrict__ otre, const float* __restrict__ otim,
    const float* __restrict__ Sarr, const float* __restrict__ alpha,
    float* __restrict__ MTre, float* __restrict__ MTim, float* __restrict__ cvar){
  __shared__ float red[256];
  const int d = blockIdx.y;
  const int p = blockIdx.x*256 + threadIdx.x;
  float contrib = 0.f;
  if (p < NN){
    float orv = otre[p], oiv = otim[p];
    float B2 = orv*orv + oiv*oiv;
    size_t idx = (size_t)d*NN + p;
    float dv = B2 + expf(alpha[d]) * Sarr[idx];
    MTre[idx] = orv / dv;
    MTim[idx] = -oiv / dv;
    contrib = B2 / (dv*dv);
  }
  red[threadIdx.x] = contrib; __syncthreads();
  for (int s = 128; s > 0; s >>= 1){
    if (threadIdx.x < s) red[threadIdx.x] += red[threadIdx.x+s];
    __syncthreads();
  }
  if (threadIdx.x == 0) atomicAdd(&cvar[d], red[0]);
}

__global__ void cstdn_k(const float* __restrict__ stdn, const float* __restrict__ cvar,
                        float* __restrict__ out){
  int t = threadIdx.x;
  if (t >= NB*ND) return;
  int b = t >> 2, d = t & 3;
  float s = stdn[b];
  out[(size_t)NB*ND*NPIX + t] = sqrtf(s*s*cvar[d]*(1.0f/(float)NN));
}

// ================= pad + fused edge-taper (border-only direct circular blur) =================
// slab(r,c) = xp2(c, r) as bf16 hi/lo pairs. Interior: xp2 = xp. Border (within 9 px):
// xp2 = t*xp + (1-t)*blur, blur = exact 81-tap circular conv (== ifft2(fft2(xp)*otf)).
__global__ __launch_bounds__(256) void pad_taper_k(const float* __restrict__ x,
                                                   const float* __restrict__ bk,
                                                   const float* __restrict__ r_row,
                                                   const float* __restrict__ r_col,
                                                   u16* __restrict__ MA){
  int idx = blockIdx.x*256 + threadIdx.x;
  if (idx >= NB*NN) return;
  int q = idx / NN, p = idx % NN;
  int r = p / NP, c = p % NP;       // slab coords; image coords: I=c (row), J=r (col)
  const float* xq = x + (size_t)q*NPIX;
  auto XP = [&](int ii, int jj)->float{
    int si = ii - 4; si = (si < 0) ? (-si-1) : ((si >= HH) ? (2*HH-1-si) : si);
    int sj = jj - 4; sj = (sj < 0) ? (-sj-1) : ((sj >= HH) ? (2*HH-1-sj) : sj);
    return xq[(size_t)si*HH + sj];
  };
  const int I = c, J = r;
  float v = XP(I, J);
  if (I < 9 || I >= 511 || J < 9 || J >= 511){
    float brv = (I < 9) ? r_row[I] : ((I >= 511) ? r_row[519-I] : 0.f);
    float bcv = (J < 9) ? r_col[J] : ((J >= 511) ? r_col[519-J] : 0.f);
    brv /= r_row[0]; bcv /= r_col[0];
    float t = (1.f - brv) * (1.f - bcv);
    float blur = 0.f;
    for (int a = 0; a < 9; ++a){
      int ii = wrap520(I - a + 4);
      for (int b2 = 0; b2 < 9; ++b2){
        int jj = wrap520(J - b2 + 4);
        blur += bk[a*9+b2] * XP(ii, jj);
      }
    }
    v = t*v + (1.f - t)*blur;
  }
  int pair = q >> 1, im = q & 1;
  u16 h, lo; split2(v, h, lo);
  size_t o = (size_t)pair*PLANE + (size_t)r*KS + c;
  MA[(size_t)(im*2+0)*S8P + o] = h;
  MA[(size_t)(im*2+1)*S8P + o] = lo;
}

// OUT = IN .* mask (complex, mask f32 per-element), both bf16-pair slabs
__global__ __launch_bounds__(256) void maskT_k(const u16* __restrict__ IN, u16* __restrict__ OUT,
                                               const float* __restrict__ Mre, const float* __restrict__ Mim){
  int idx = blockIdx.x*256 + threadIdx.x;
  if (idx >= NPAIR*NN) return;
  int pr = idx / NN, p = idx % NN;
  int r = p / NP, c = p % NP;
  size_t o = (size_t)pr*PLANE + (size_t)r*KS + c;
  float vr = rec(IN[0*S8P + o], IN[1*S8P + o]);
  float vi = rec(IN[2*S8P + o], IN[3*S8P + o]);
  float mr = Mre[p], mi = Mim[p];
  float wr = vr*mr - vi*mi;
  float wi = vr*mi + vi*mr;
  u16 h, lo;
  split2(wr,h,lo); OUT[0*S8P+o]=h; OUT[1*S8P+o]=lo;
  split2(wi,h,lo); OUT[2*S8P+o]=h; OUT[3*S8P+o]=lo;
}

// ================= MFMA complex GEMM: OUT(m,n) = sum_k P(m,k) * Qtile[n][k] =================
template<int CROP>
__global__ __launch_bounds__(256) void gemm_k(
    const u16* __restrict__ P, size_t pPlane, size_t pPair,
    const u16* __restrict__ Q, size_t qPlane, size_t qPair,
    u16* __restrict__ O, float* __restrict__ cropOut, int dIdx)
{
  __shared__ u16 lds[8*2048];   // 8 planes x [64 rows][32 k] bf16 (P:0-3, Q:4-7)
  const int tid = threadIdx.x;
  const int l = tid & 63, w = tid >> 6;
  const int b = blockIdx.z;
  const int R0 = blockIdx.y * 64, C0 = blockIdx.x * 64;

  const int rt = w*16 + (l >> 2);
  const int csrc = (l & 3) ^ ((rt >> 1) & 3);
  const size_t pOff = (size_t)b*pPair + (size_t)(R0+rt)*KS + (size_t)(csrc*8);
  const size_t qOff = (size_t)b*qPair + (size_t)(C0+rt)*KS + (size_t)(csrc*8);
  u16* ldsW = lds + w*512;

  const int lm = l & 15, lc = l >> 4;
  const int wm = w >> 1, wn = w & 1;

  f32x4 zero4 = {0.f, 0.f, 0.f, 0.f};
  f32x4 aRe[2][2], aIm[2][2];
  #pragma unroll
  for (int i = 0; i < 2; ++i)
    #pragma unroll
    for (int j = 0; j < 2; ++j){ aRe[i][j] = zero4; aIm[i][j] = zero4; }

  #pragma unroll 1
  for (int k0 = 0; k0 < KS; k0 += 32){
    #pragma unroll
    for (int p = 0; p < 4; ++p){
      gll16(P + (size_t)p*pPlane + pOff + k0, ldsW + p*2048);
      gll16(Q + (size_t)p*qPlane + qOff + k0, ldsW + (4+p)*2048);
    }
    __syncthreads();

    bf16x8 pf[2][4], qf[2][4];
    #pragma unroll
    for (int mi = 0; mi < 2; ++mi){
      int r = wm*32 + mi*16 + lm;
      int co = ((lc ^ ((r >> 1) & 3)) << 3);
      #pragma unroll
      for (int p = 0; p < 4; ++p)
        pf[mi][p] = *(const bf16x8*)(lds + p*2048 + r*32 + co);
    }
    #pragma unroll
    for (int ni = 0; ni < 2; ++ni){
      int r = wn*32 + ni*16 + lm;
      int co = ((lc ^ ((r >> 1) & 3)) << 3);
      #pragma unroll
      for (int p = 0; p < 4; ++p)
        qf[ni][p] = *(const bf16x8*)(lds + (4+p)*2048 + r*32 + co);
    }

    #pragma unroll
    for (int ni = 0; ni < 2; ++ni){
      bf16x8 nih = qf[ni][2] ^ (short)0x8000;   // -im_hi
      bf16x8 nil = qf[ni][3] ^ (short)0x8000;   // -im_lo
      #pragma unroll
      for (int mi = 0; mi < 2; ++mi){
        f32x4 r = aRe[mi][ni], im = aIm[mi][ni];
        r = MF(pf[mi][0], qf[ni][0], r);    // re*re (hi*hi, hi*lo, lo*hi)
        r = MF(pf[mi][0], qf[ni][1], r);
        r = MF(pf[mi][1], qf[ni][0], r);
        r = MF(pf[mi][2], nih, r);          // -im*im
        r = MF(pf[mi][2], nil, r);
        r = MF(pf[mi][3], nih, r);
        im = MF(pf[mi][0], qf[ni][2], im);  // re*im
        im = MF(pf[mi][0], qf[ni][3], im);
        im = MF(pf[mi][1], qf[ni][2], im);
        im = MF(pf[mi][2], qf[ni][0], im);  // im*re
        im = MF(pf[mi][2], qf[ni][1], im);
        im = MF(pf[mi][3], qf[ni][0], im);
        aRe[mi][ni] = r; aIm[mi][ni] = im;
      }
    }
    __syncthreads();
  }

  // epilogue
  #pragma unroll
  for (int mi = 0; mi < 2; ++mi)
    #pragma unroll
    for (int ni = 0; ni < 2; ++ni){
      int cb = C0 + wn*32 + ni*16 + lm;
      int rb = R0 + wm*32 + mi*16 + lc*4;
      #pragma unroll
      for (int e = 0; e < 4; ++e){
        int rr = rb + e;
        float vr = aRe[mi][ni][e], vi = aIm[mi][ni][e];
        if (CROP){
          if (rr >= 4 && rr < 516 && cb >= 4 && cb < 516){
            size_t px = (size_t)(rr-4)*HH + (cb-4);
            cropOut[((size_t)(2*b  )*ND + dIdx)*NPIX + px] = vr;
            cropOut[((size_t)(2*b+1)*ND + dIdx)*NPIX + px] = vi;
          }
        } else {
          if (rr < NP && cb < NP){
            size_t o = (size_t)b*PLANE + (size_t)rr*KS + cb;
            u16 h, lo;
            split2(vr, h, lo); O[0*S8P+o] = h; O[1*S8P+o] = lo;
            split2(vi, h, lo); O[2*S8P+o] = h; O[3*S8P+o] = lo;
          }
        }
      }
    }
}

// ================= host =================

extern "C" void kernel_launch(void* const* d_in, const int* in_sizes, int n_in,
                              void* d_out, int out_size, void* d_ws, size_t ws_size,
                              hipStream_t stream){
  const float* x     = (const float*)d_in[0];
  const float* bk    = (const float*)d_in[1];
  const float* stdn  = (const float*)d_in[2];
  const float* cw    = (const float*)d_in[3];
  const float* scale = (const float*)d_in[4];
  const float* alpha = (const float*)d_in[5];
  float* out = (float*)d_out;

  char* base = (char*)d_ws;
  size_t off = 0;
  auto alloc = [&](size_t bytes)->void*{
    void* p = base + off;
    off += (bytes + 255) & ~(size_t)255;
    return p;
  };
  u16* MA = (u16*)alloc(4*S8P*sizeof(u16));
  u16* MB = (u16*)alloc(4*S8P*sizeof(u16));
  u16* MC = (u16*)alloc(4*S8P*sizeof(u16));
  u16* WF = (u16*)alloc(4*PLANE*sizeof(u16));
  u16* WI = (u16*)alloc(4*PLANE*sizeof(u16));
  size_t zeroBytes = off;   // slabs + W get memset to 0 (padded regions must be 0)
  float* otre = (float*)alloc(NN*4);
  float* otim = (float*)alloc(NN*4);
  float* ST   = (float*)alloc((size_t)ND*NN*4);
  float* MTre = (float*)alloc((size_t)ND*NN*4);
  float* MTim = (float*)alloc((size_t)ND*NN*4);
  float* e5re = (float*)alloc(NP*5*4);
  float* e5im = (float*)alloc(NP*5*4);
  float* r_row = (float*)alloc(64);
  float* r_col = (float*)alloc(64);
  float* wn   = (float*)alloc(ND*NF*25*4);
  float* cvar = (float*)alloc(64);
  if (off > ws_size) return;  // insufficient workspace

  hipMemsetAsync(d_ws, 0, zeroBytes, stream);
  hipMemsetAsync(cvar, 0, ND*sizeof(float), stream);

  build_Wpair_k<<<((int)PLANE+255)/256, 256, 0, stream>>>(WF, WI);
  build_e5_k   <<<(NP*5+255)/256, 256, 0, stream>>>(e5re, e5im);
  build_otfT_k <<<(NN+255)/256, 256, 0, stream>>>(bk, otre, otim);
  taper_r_k    <<<1, 32, 0, stream>>>(bk, r_row, r_col);
  norm_w_k     <<<1, 128, 0, stream>>>(cw, scale, wn);
  S_k          <<<(ND*NN+255)/256, 256, 0, stream>>>(wn, e5re, e5im, ST);
  {
    dim3 gd((NN+255)/256, ND);
    denomMTcvar_k<<<gd, 256, 0, stream>>>(otre, otim, ST, alpha, MTre, MTim, cvar);
  }
  cstdn_k      <<<1, 64, 0, stream>>>(stdn, cvar, out);
  pad_taper_k  <<<(NB*NN+255)/256, 256, 0, stream>>>(x, bk, r_row, r_col, MA);  // xp2T direct

  dim3 gg(9, 9, NPAIR);
  const size_t BP = S8P, BW = PLANE;
  // fft2(xp2): C5 = W*xp2   (P=Wf, Q=xp2T)   -> MB
  gemm_k<0><<<gg,256,0,stream>>>(WF,BW,0, MA,BP,PLANE, MB, nullptr, 0);
  // F2^T                    (P=Wf, Q=C5)     -> MC
  gemm_k<0><<<gg,256,0,stream>>>(WF,BW,0, MB,BP,PLANE, MC, nullptr, 0);
  for (int d = 0; d < ND; ++d){
    // A7 = F2^T .* MT_d     -> MA
    maskT_k<<<(NPAIR*NN+255)/256, 256, 0, stream>>>(MC, MA, MTre + (size_t)d*NN, MTim + (size_t)d*NN);
    // C7 = Wi*Xf_d          (P=Wi, Q=A7)     -> MB
    gemm_k<0><<<gg,256,0,stream>>>(WI,BW,0, MA,BP,PLANE, MB, nullptr, 0);
    // out_d = C7*Wi (crop)  (P=C7, Q=Wi)
    gemm_k<1><<<gg,256,0,stream>>>(MB,BP,PLANE, WI,BW,0, nullptr, out, d);
  }
}

// Round 4
// 713.874 us; speedup vs baseline: 11.3765x; 1.1356x over previous
//
#include <hip/hip_runtime.h>
#include <math.h>

#define NP    520
#define NN    (520*520)
#define HH    512
#define NPIX  (512*512)
#define NB    16
#define NPAIR 8
#define ND    4
#define NF    24
#define KS    544               // padded row stride (elements)
#define RS    576               // padded row count
#define PLANE ((size_t)RS*KS)   // elements per plane
#define S8P   (8*PLANE)         // batched plane stride
#define E9SZ  (NP*9)
#define CSZ   (ND*9*NP)
#define TWO_PI 6.283185307179586f

typedef unsigned short u16;
typedef __attribute__((ext_vector_type(8))) short bf16x8;
typedef __attribute__((ext_vector_type(4))) float f32x4;

__device__ __forceinline__ int wrap520(int t){ t %= NP; return t < 0 ? t + NP : t; }

__device__ __forceinline__ u16 f2bf(float f){
  unsigned u = __float_as_uint(f);
  u += 0x7FFFu + ((u >> 16) & 1u);
  return (u16)(u >> 16);
}
__device__ __forceinline__ void split2(float f, u16& hi, u16& lo){
  hi = f2bf(f);
  float fh = __uint_as_float(((unsigned)hi) << 16);
  lo = f2bf(f - fh);
}
__device__ __forceinline__ float rec(u16 h, u16 l){
  return __uint_as_float(((unsigned)h) << 16) + __uint_as_float(((unsigned)l) << 16);
}
__device__ __forceinline__ void gll16(const u16* g, u16* l){
  __builtin_amdgcn_global_load_lds(
      (const __attribute__((address_space(1))) void*)g,
      (__attribute__((address_space(3))) void*)l, 16, 0, 0);
}
#define MF(a,b,c) __builtin_amdgcn_mfma_f32_16x16x32_bf16((a),(b),(c),0,0,0)

// ================= setup kernels =================

// W slabs: 2 planes {re, im} each (single bf16 precision), padded region = 0
__global__ __launch_bounds__(256) void build_Wpair_k(u16* __restrict__ wf, u16* __restrict__ wi){
  int idx = blockIdx.x*256 + threadIdx.x;
  if (idx >= (int)PLANE) return;
  int r = idx / KS, k = idx % KS;
  float fr=0.f, fi=0.f, ir=0.f, ii=0.f;
  if (r < NP && k < NP){
    int m = (int)(((long long)r * (long long)k) % NP);
    float ang = TWO_PI * (float)m / (float)NP;
    float s, c; sincosf(ang, &s, &c);
    fr = c; fi = -s;
    ir = c * (1.0f/NP); ii = s * (1.0f/NP);
  }
  wf[0*PLANE+idx] = f2bf(fr); wf[1*PLANE+idx] = f2bf(fi);
  wi[0*PLANE+idx] = f2bf(ir); wi[1*PLANE+idx] = f2bf(ii);
}

// e9 twiddles: e9re[u*9+t] = cos(2pi*u*(t-4)/520), e9im = -sin(...)
__global__ __launch_bounds__(256) void e9_k(float* __restrict__ e9){
  int idx = blockIdx.x*256 + threadIdx.x;
  if (idx >= NP*9) return;
  int u = idx / 9, t = idx % 9;
  int m = wrap520(u*(t-4));
  float ang = TWO_PI * (float)m / (float)NP;
  float s, c; sincosf(ang, &s, &c);
  e9[idx] = c; e9[E9SZ + idx] = -s;
}

// blur row table: T[i][v] = sum_j bk[i,j] * e_v[j-4]  (complex)
__global__ void bkT_k(const float* __restrict__ bk, const float* __restrict__ e9,
                      float* __restrict__ T){
  int idx = blockIdx.x*blockDim.x + threadIdx.x;
  if (idx >= 9*NP) return;
  int i = idx / NP, v = idx % NP;
  float tr = 0.f, ti = 0.f;
  #pragma unroll
  for (int j = 0; j < 9; ++j){
    float w = bk[i*9+j];
    tr += w * e9[v*9+j];
    ti += w * e9[E9SZ + v*9+j];
  }
  T[idx] = tr; T[9*NP + idx] = ti;
}

// transposed blur OTF via T-table: otfT[v*NP+u] = otf(u,v)
__global__ __launch_bounds__(256) void otfT2_k(const float* __restrict__ T, const float* __restrict__ e9,
                                               float* __restrict__ otre, float* __restrict__ otim){
  int idx = blockIdx.x*256 + threadIdx.x;
  if (idx >= NN) return;
  int u = idx % NP, v = idx / NP;
  float ar = 0.f, ai = 0.f;
  #pragma unroll
  for (int i = 0; i < 9; ++i){
    float er = e9[u*9+i], ei = e9[E9SZ + u*9+i];
    float tr = T[i*NP+v], ti = T[9*NP + i*NP+v];
    ar += er*tr - ei*ti;
    ai += er*ti + ei*tr;
  }
  otre[idx] = ar; otim[idx] = ai;
}

__global__ void taper_r_k(const float* __restrict__ bk, float* __restrict__ r_row, float* __restrict__ r_col){
  int t = threadIdx.x;
  if (t >= 18) return;
  int k = t % 9;
  bool rowp = (t < 9);
  float proj[9];
  for (int m = 0; m < 9; ++m){
    float a = 0.f;
    for (int j = 0; j < 9; ++j) a += rowp ? bk[m*9+j] : bk[j*9+m];
    proj[m] = a;
  }
  float acc = 0.f;
  for (int m = 0; m + k < 9; ++m) acc += proj[m] * proj[m+k];
  (rowp ? r_row : r_col)[k] = acc;
}

__global__ void norm_w_k(const float* __restrict__ cw, const float* __restrict__ scale,
                         float* __restrict__ wn){
  int idx = blockIdx.x*blockDim.x + threadIdx.x;
  if (idx >= ND*NF) return;
  const float* wp = cw + idx*25;
  float mean = 0.f;
  for (int k = 0; k < 25; ++k) mean += wp[k];
  mean *= (1.0f/25.0f);
  float ss = 0.f;
  for (int k = 0; k < 25; ++k){ float d = wp[k]-mean; ss += d*d; }
  float sc = scale[idx] / sqrtf(ss);
  for (int k = 0; k < 25; ++k) wn[idx*25+k] = (wp[k]-mean)*sc;
}

// filter autocorrelation: R[d][di+4][dj+4] = sum_f sum_ij w[i,j]*w[i-di,j-dj]
__global__ void R_k(const float* __restrict__ wn, float* __restrict__ R){
  int idx = blockIdx.x*blockDim.x + threadIdx.x;
  if (idx >= ND*81) return;
  int d = idx / 81, t = idx % 81;
  int di = t/9 - 4, dj = t%9 - 4;
  int i0 = di > 0 ? di : 0, i1 = di < 0 ? 4+di : 4;
  int j0 = dj > 0 ? dj : 0, j1 = dj < 0 ? 4+dj : 4;
  float acc = 0.f;
  for (int f = 0; f < NF; ++f){
    const float* w = wn + (d*NF+f)*25;
    for (int i = i0; i <= i1; ++i)
      for (int j = j0; j <= j1; ++j)
        acc += w[i*5+j] * w[(i-di)*5 + (j-dj)];
  }
  R[idx] = acc;
}

// C table: C[d][t][v] = sum_s R[d][t][s] * e_v[s-4]  (complex)
__global__ void C_k(const float* __restrict__ R, const float* __restrict__ e9,
                    float* __restrict__ Ctab){
  int idx = blockIdx.x*blockDim.x + threadIdx.x;
  if (idx >= ND*9*NP) return;
  int v = idx % NP, t9 = idx / NP;   // t9 = d*9+t
  int d = t9 / 9, t = t9 % 9;
  float cr = 0.f, ci = 0.f;
  #pragma unroll
  for (int s = 0; s < 9; ++s){
    float r = R[d*81 + t*9 + s];
    cr += r * e9[v*9+s];
    ci += r * e9[E9SZ + v*9+s];
  }
  Ctab[idx] = cr; Ctab[CSZ + idx] = ci;
}

// wiener masks MT_d = conj(otfT)/denT with inline S (from C table) + fused cvar reduction
__global__ __launch_bounds__(256) void denomMTcvar_k(
    const float* __restrict__ otre, const float* __restrict__ otim,
    const float* __restrict__ Ctab, const float* __restrict__ e9,
    const float* __restrict__ alpha,
    float* __restrict__ MTre, float* __restrict__ MTim, float* __restrict__ cvar){
  __shared__ float red[256];
  const int d = blockIdx.y;
  const int p = blockIdx.x*256 + threadIdx.x;
  float contrib = 0.f;
  if (p < NN){
    int u = p % NP, v = p / NP;
    float S = 0.f;
    #pragma unroll
    for (int t = 0; t < 9; ++t){
      float er = e9[u*9+t], ei = e9[E9SZ + u*9+t];
      float cr = Ctab[(d*9+t)*NP + v], ci = Ctab[CSZ + (d*9+t)*NP + v];
      S += er*cr - ei*ci;
    }
    float orv = otre[p], oiv = otim[p];
    float B2 = orv*orv + oiv*oiv;
    size_t idx = (size_t)d*NN + p;
    float dv = B2 + expf(alpha[d]) * S;
    MTre[idx] = orv / dv;
    MTim[idx] = -oiv / dv;
    contrib = B2 / (dv*dv);
  }
  red[threadIdx.x] = contrib; __syncthreads();
  for (int s = 128; s > 0; s >>= 1){
    if (threadIdx.x < s) red[threadIdx.x] += red[threadIdx.x+s];
    __syncthreads();
  }
  if (threadIdx.x == 0) atomicAdd(&cvar[d], red[0]);
}

__global__ void cstdn_k(const float* __restrict__ stdn, const float* __restrict__ cvar,
                        float* __restrict__ out){
  int t = threadIdx.x;
  if (t >= NB*ND) return;
  int b = t >> 2, d = t & 3;
  float s = stdn[b];
  out[(size_t)NB*ND*NPIX + t] = sqrtf(s*s*cvar[d]*(1.0f/(float)NN));
}

// ================= pad + fused edge-taper (vectorized: 8 elems/thread) =================
__global__ __launch_bounds__(256) void pad_taper_k(const float* __restrict__ x,
                                                   const float* __restrict__ bk,
                                                   const float* __restrict__ r_row,
                                                   const float* __restrict__ r_col,
                                                   u16* __restrict__ MA){
  int idx = blockIdx.x*256 + threadIdx.x;
  if (idx >= NB*NP*65) return;
  int q = idx / (NP*65), rem = idx % (NP*65);
  int r = rem / 65, c0 = (rem % 65)*8;
  const float* xq = x + (size_t)q*NPIX;
  auto XP = [&](int ii, int jj)->float{
    int si = ii - 4; si = (si < 0) ? (-si-1) : ((si >= HH) ? (2*HH-1-si) : si);
    int sj = jj - 4; sj = (sj < 0) ? (-sj-1) : ((sj >= HH) ? (2*HH-1-sj) : sj);
    return xq[(size_t)si*HH + sj];
  };
  const int J = r;
  bf16x8 vh, vl;
  #pragma unroll
  for (int e = 0; e < 8; ++e){
    int I = c0 + e;
    float v = XP(I, J);
    if (I < 9 || I >= 511 || J < 9 || J >= 511){
      float brv = (I < 9) ? r_row[I] : ((I >= 511) ? r_row[519-I] : 0.f);
      float bcv = (J < 9) ? r_col[J] : ((J >= 511) ? r_col[519-J] : 0.f);
      brv /= r_row[0]; bcv /= r_col[0];
      float t = (1.f - brv) * (1.f - bcv);
      float blur = 0.f;
      for (int a = 0; a < 9; ++a){
        int ii = wrap520(I - a + 4);
        for (int b2 = 0; b2 < 9; ++b2){
          int jj = wrap520(J - b2 + 4);
          blur += bk[a*9+b2] * XP(ii, jj);
        }
      }
      v = t*v + (1.f - t)*blur;
    }
    u16 h, lo; split2(v, h, lo);
    vh[e] = (short)h; vl[e] = (short)lo;
  }
  int pair = q >> 1, im = q & 1;
  size_t o = (size_t)pair*PLANE + (size_t)r*KS + c0;
  *(bf16x8*)(MA + (size_t)(im*2+0)*S8P + o) = vh;
  *(bf16x8*)(MA + (size_t)(im*2+1)*S8P + o) = vl;
}

// OUT = IN .* mask (complex), vectorized 8 elems/thread
__global__ __launch_bounds__(256) void maskT_k(const u16* __restrict__ IN, u16* __restrict__ OUT,
                                               const float* __restrict__ Mre, const float* __restrict__ Mim){
  int idx = blockIdx.x*256 + threadIdx.x;
  if (idx >= NPAIR*NP*65) return;
  int pr = idx / (NP*65), rem = idx % (NP*65);
  int r = rem / 65, c0 = (rem % 65)*8;
  size_t o = (size_t)pr*PLANE + (size_t)r*KS + c0;
  bf16x8 rh = *(const bf16x8*)(IN + 0*S8P + o);
  bf16x8 rl = *(const bf16x8*)(IN + 1*S8P + o);
  bf16x8 ih = *(const bf16x8*)(IN + 2*S8P + o);
  bf16x8 il = *(const bf16x8*)(IN + 3*S8P + o);
  int p0 = r*NP + c0;
  bf16x8 orh, orl, oih, oil;
  #pragma unroll
  for (int e = 0; e < 8; ++e){
    float vr = rec((u16)rh[e], (u16)rl[e]);
    float vi = rec((u16)ih[e], (u16)il[e]);
    float mr = Mre[p0+e], mi = Mim[p0+e];
    float wr = vr*mr - vi*mi;
    float wi = vr*mi + vi*mr;
    u16 h, lo;
    split2(wr, h, lo); orh[e] = (short)h; orl[e] = (short)lo;
    split2(wi, h, lo); oih[e] = (short)h; oil[e] = (short)lo;
  }
  *(bf16x8*)(OUT + 0*S8P + o) = orh;
  *(bf16x8*)(OUT + 1*S8P + o) = orl;
  *(bf16x8*)(OUT + 2*S8P + o) = oih;
  *(bf16x8*)(OUT + 3*S8P + o) = oil;
}

// ================= MFMA complex GEMM: OUT(m,n) = sum_k P(m,k)*Q(n,k) =================
// One operand is the W matrix (2 planes {re,im}, bf16), the other is data
// (4 planes {rehi,relo,imhi,imlo}). PW=1: P is W. PW=0: Q is W.
template<int PW, int CROP>
__global__ __launch_bounds__(256) void gemm_k(
    const u16* __restrict__ P, size_t pPlane, size_t pPair,
    const u16* __restrict__ Q, size_t qPlane, size_t qPair,
    u16* __restrict__ O, float* __restrict__ cropOut, int dIdx)
{
  constexpr int NPP = PW ? 2 : 4;
  constexpr int NPQ = PW ? 4 : 2;
  __shared__ u16 lds[(NPP+NPQ)*2048];   // planes x [64 rows][32 k] bf16
  const int tid = threadIdx.x;
  const int l = tid & 63, w = tid >> 6;
  const int b = blockIdx.z;
  const int R0 = blockIdx.y * 64, C0 = blockIdx.x * 64;

  const int rt = w*16 + (l >> 2);
  const int csrc = (l & 3) ^ ((rt >> 1) & 3);
  const size_t pOff = (size_t)b*pPair + (size_t)(R0+rt)*KS + (size_t)(csrc*8);
  const size_t qOff = (size_t)b*qPair + (size_t)(C0+rt)*KS + (size_t)(csrc*8);
  u16* ldsW = lds + w*512;

  const int lm = l & 15, lc = l >> 4;
  const int wm = w >> 1, wn = w & 1;

  f32x4 zero4 = {0.f, 0.f, 0.f, 0.f};
  f32x4 aRe[2][2], aIm[2][2];
  #pragma unroll
  for (int i = 0; i < 2; ++i)
    #pragma unroll
    for (int j = 0; j < 2; ++j){ aRe[i][j] = zero4; aIm[i][j] = zero4; }

  #pragma unroll 1
  for (int k0 = 0; k0 < KS; k0 += 32){
    #pragma unroll
    for (int p = 0; p < NPP; ++p)
      gll16(P + (size_t)p*pPlane + pOff + k0, ldsW + p*2048);
    #pragma unroll
    for (int p = 0; p < NPQ; ++p)
      gll16(Q + (size_t)p*qPlane + qOff + k0, ldsW + (NPP+p)*2048);
    __syncthreads();

    bf16x8 pf[2][NPP], qf[2][NPQ];
    #pragma unroll
    for (int mi = 0; mi < 2; ++mi){
      int r = wm*32 + mi*16 + lm;
      int co = ((lc ^ ((r >> 1) & 3)) << 3);
      #pragma unroll
      for (int p = 0; p < NPP; ++p)
        pf[mi][p] = *(const bf16x8*)(lds + p*2048 + r*32 + co);
    }
    #pragma unroll
    for (int ni = 0; ni < 2; ++ni){
      int r = wn*32 + ni*16 + lm;
      int co = ((lc ^ ((r >> 1) & 3)) << 3);
      #pragma unroll
      for (int p = 0; p < NPQ; ++p)
        qf[ni][p] = *(const bf16x8*)(lds + (NPP+p)*2048 + r*32 + co);
    }

    if (PW){
      // P = W{re,im}; Q = data{rh,rl,ih,il}
      #pragma unroll
      for (int mi = 0; mi < 2; ++mi){
        bf16x8 nw1 = pf[mi][1] ^ (short)0x8000;   // -W.im
        #pragma unroll
        for (int ni = 0; ni < 2; ++ni){
          f32x4 r = aRe[mi][ni], im = aIm[mi][ni];
          r  = MF(pf[mi][0], qf[ni][0], r);
          r  = MF(pf[mi][0], qf[ni][1], r);
          r  = MF(nw1,       qf[ni][2], r);
          r  = MF(nw1,       qf[ni][3], r);
          im = MF(pf[mi][0], qf[ni][2], im);
          im = MF(pf[mi][0], qf[ni][3], im);
          im = MF(pf[mi][1], qf[ni][0], im);
          im = MF(pf[mi][1], qf[ni][1], im);
          aRe[mi][ni] = r; aIm[mi][ni] = im;
        }
      }
    } else {
      // P = data{rh,rl,ih,il}; Q = W{re,im}
      #pragma unroll
      for (int ni = 0; ni < 2; ++ni){
        bf16x8 nw1 = qf[ni][1] ^ (short)0x8000;   // -W.im
        #pragma unroll
        for (int mi = 0; mi < 2; ++mi){
          f32x4 r = aRe[mi][ni], im = aIm[mi][ni];
          r  = MF(pf[mi][0], qf[ni][0], r);
          r  = MF(pf[mi][1], qf[ni][0], r);
          r  = MF(pf[mi][2], nw1,       r);
          r  = MF(pf[mi][3], nw1,       r);
          im = MF(pf[mi][0], qf[ni][1], im);
          im = MF(pf[mi][1], qf[ni][1], im);
          im = MF(pf[mi][2], qf[ni][0], im);
          im = MF(pf[mi][3], qf[ni][0], im);
          aRe[mi][ni] = r; aIm[mi][ni] = im;
        }
      }
    }
    __syncthreads();
  }

  // epilogue
  #pragma unroll
  for (int mi = 0; mi < 2; ++mi)
    #pragma unroll
    for (int ni = 0; ni < 2; ++ni){
      int cb = C0 + wn*32 + ni*16 + lm;
      int rb = R0 + wm*32 + mi*16 + lc*4;
      #pragma unroll
      for (int e = 0; e < 4; ++e){
        int rr = rb + e;
        float vr = aRe[mi][ni][e], vi = aIm[mi][ni][e];
        if (CROP){
          if (rr >= 4 && rr < 516 && cb >= 4 && cb < 516){
            size_t px = (size_t)(rr-4)*HH + (cb-4);
            cropOut[((size_t)(2*b  )*ND + dIdx)*NPIX + px] = vr;
            cropOut[((size_t)(2*b+1)*ND + dIdx)*NPIX + px] = vi;
          }
        } else {
          if (rr < NP && cb < NP){
            size_t o = (size_t)b*PLANE + (size_t)rr*KS + cb;
            u16 h, lo;
            split2(vr, h, lo); O[0*S8P+o] = h; O[1*S8P+o] = lo;
            split2(vi, h, lo); O[2*S8P+o] = h; O[3*S8P+o] = lo;
          }
        }
      }
    }
}

// ================= host =================

extern "C" void kernel_launch(void* const* d_in, const int* in_sizes, int n_in,
                              void* d_out, int out_size, void* d_ws, size_t ws_size,
                              hipStream_t stream){
  const float* x     = (const float*)d_in[0];
  const float* bk    = (const float*)d_in[1];
  const float* stdn  = (const float*)d_in[2];
  const float* cw    = (const float*)d_in[3];
  const float* scale = (const float*)d_in[4];
  const float* alpha = (const float*)d_in[5];
  float* out = (float*)d_out;

  char* base = (char*)d_ws;
  size_t off = 0;
  auto alloc = [&](size_t bytes)->void*{
    void* p = base + off;
    off += (bytes + 255) & ~(size_t)255;
    return p;
  };
  u16* MA = (u16*)alloc(4*S8P*sizeof(u16));
  u16* MB = (u16*)alloc(4*S8P*sizeof(u16));
  u16* MC = (u16*)alloc(4*S8P*sizeof(u16));
  u16* WF = (u16*)alloc(2*PLANE*sizeof(u16));
  u16* WI = (u16*)alloc(2*PLANE*sizeof(u16));
  size_t zeroBytes = off;   // slabs + W memset to 0 (padded regions must be 0)
  float* otre = (float*)alloc(NN*4);
  float* otim = (float*)alloc(NN*4);
  float* MTre = (float*)alloc((size_t)ND*NN*4);
  float* MTim = (float*)alloc((size_t)ND*NN*4);
  float* e9   = (float*)alloc(2*E9SZ*4);
  float* Tb   = (float*)alloc(2*9*NP*4);
  float* Rarr = (float*)alloc(ND*81*4);
  float* Ctab = (float*)alloc(2*CSZ*4);
  float* r_row = (float*)alloc(64);
  float* r_col = (float*)alloc(64);
  float* wn   = (float*)alloc(ND*NF*25*4);
  float* cvar = (float*)alloc(64);
  if (off > ws_size) return;  // insufficient workspace

  hipMemsetAsync(d_ws, 0, zeroBytes, stream);
  hipMemsetAsync(cvar, 0, ND*sizeof(float), stream);

  build_Wpair_k<<<((int)PLANE+255)/256, 256, 0, stream>>>(WF, WI);
  e9_k         <<<(NP*9+255)/256, 256, 0, stream>>>(e9);
  taper_r_k    <<<1, 32, 0, stream>>>(bk, r_row, r_col);
  norm_w_k     <<<1, 128, 0, stream>>>(cw, scale, wn);
  bkT_k        <<<(9*NP+255)/256, 256, 0, stream>>>(bk, e9, Tb);
  R_k          <<<2, 256, 0, stream>>>(wn, Rarr);
  otfT2_k      <<<(NN+255)/256, 256, 0, stream>>>(Tb, e9, otre, otim);
  C_k          <<<(ND*9*NP+255)/256, 256, 0, stream>>>(Rarr, e9, Ctab);
  {
    dim3 gd((NN+255)/256, ND);
    denomMTcvar_k<<<gd, 256, 0, stream>>>(otre, otim, Ctab, e9, alpha, MTre, MTim, cvar);
  }
  cstdn_k      <<<1, 64, 0, stream>>>(stdn, cvar, out);
  pad_taper_k  <<<(NB*NP*65+255)/256, 256, 0, stream>>>(x, bk, r_row, r_col, MA);

  dim3 gg(9, 9, NPAIR);
  const size_t BP = S8P, BW = PLANE;
  // fft2(xp2): C5 = W*xp2   (P=Wf, Q=xp2T)   -> MB
  gemm_k<1,0><<<gg,256,0,stream>>>(WF,BW,0, MA,BP,PLANE, MB, nullptr, 0);
  // F2^T                    (P=Wf, Q=C5)     -> MC
  gemm_k<1,0><<<gg,256,0,stream>>>(WF,BW,0, MB,BP,PLANE, MC, nullptr, 0);
  for (int d = 0; d < ND; ++d){
    // A7 = F2^T .* MT_d     -> MA
    maskT_k<<<(NPAIR*NP*65+255)/256, 256, 0, stream>>>(MC, MA, MTre + (size_t)d*NN, MTim + (size_t)d*NN);
    // C7 = Wi*Xf_d          (P=Wi, Q=A7)     -> MB
    gemm_k<1,0><<<gg,256,0,stream>>>(WI,BW,0, MA,BP,PLANE, MB, nullptr, 0);
    // out_d = C7*Wi (crop)  (P=C7, Q=Wi)
    gemm_k<0,1><<<gg,256,0,stream>>>(MB,BP,PLANE, WI,BW,0, nullptr, out, d);
  }
}

// Round 5
// 653.602 us; speedup vs baseline: 12.4256x; 1.0922x over previous
//
#include <hip/hip_runtime.h>
#include <math.h>

#define NP    520
#define NN    (520*520)
#define HH    512
#define NPIX  (512*512)
#define NB    16
#define NPAIR 8
#define ND    4
#define NF    24
#define KS    544               // padded row stride (elements)
#define RS    576               // padded row count
#define PLANE ((size_t)RS*KS)   // elements per plane
#define S8P   (8*PLANE)         // batched plane stride
#define E9SZ  (NP*9)
#define CSZ   (ND*9*NP)
#define TWO_PI 6.283185307179586f

typedef unsigned short u16;
typedef __attribute__((ext_vector_type(8))) short bf16x8;
typedef __attribute__((ext_vector_type(4))) float f32x4;

__device__ __forceinline__ int wrap520(int t){ t %= NP; return t < 0 ? t + NP : t; }

__device__ __forceinline__ u16 f2bf(float f){
  unsigned u = __float_as_uint(f);
  u += 0x7FFFu + ((u >> 16) & 1u);
  return (u16)(u >> 16);
}
__device__ __forceinline__ void split2(float f, u16& hi, u16& lo){
  hi = f2bf(f);
  float fh = __uint_as_float(((unsigned)hi) << 16);
  lo = f2bf(f - fh);
}
__device__ __forceinline__ float rec(u16 h, u16 l){
  return __uint_as_float(((unsigned)h) << 16) + __uint_as_float(((unsigned)l) << 16);
}
__device__ __forceinline__ void gll16(const u16* g, u16* l){
  __builtin_amdgcn_global_load_lds(
      (const __attribute__((address_space(1))) void*)g,
      (__attribute__((address_space(3))) void*)l, 16, 0, 0);
}
#define MF(a,b,c) __builtin_amdgcn_mfma_f32_16x16x32_bf16((a),(b),(c),0,0,0)

// ================= setup kernels =================

// W slabs: 2 planes {re, im} each (single bf16 precision), padded region = 0
__global__ __launch_bounds__(256) void build_Wpair_k(u16* __restrict__ wf, u16* __restrict__ wi){
  int idx = blockIdx.x*256 + threadIdx.x;
  if (idx >= (int)PLANE) return;
  int r = idx / KS, k = idx % KS;
  float fr=0.f, fi=0.f, ir=0.f, ii=0.f;
  if (r < NP && k < NP){
    int m = (int)(((long long)r * (long long)k) % NP);
    float ang = TWO_PI * (float)m / (float)NP;
    float s, c; sincosf(ang, &s, &c);
    fr = c; fi = -s;
    ir = c * (1.0f/NP); ii = s * (1.0f/NP);
  }
  wf[0*PLANE+idx] = f2bf(fr); wf[1*PLANE+idx] = f2bf(fi);
  wi[0*PLANE+idx] = f2bf(ir); wi[1*PLANE+idx] = f2bf(ii);
}

// e9 twiddles: e9re[u*9+t] = cos(2pi*u*(t-4)/520), e9im = -sin(...)
__global__ __launch_bounds__(256) void e9_k(float* __restrict__ e9){
  int idx = blockIdx.x*256 + threadIdx.x;
  if (idx >= NP*9) return;
  int u = idx / 9, t = idx % 9;
  int m = wrap520(u*(t-4));
  float ang = TWO_PI * (float)m / (float)NP;
  float s, c; sincosf(ang, &s, &c);
  e9[idx] = c; e9[E9SZ + idx] = -s;
}

// blur row table: T[i][v] = sum_j bk[i,j] * e_v[j-4]  (complex)
__global__ void bkT_k(const float* __restrict__ bk, const float* __restrict__ e9,
                      float* __restrict__ T){
  int idx = blockIdx.x*blockDim.x + threadIdx.x;
  if (idx >= 9*NP) return;
  int i = idx / NP, v = idx % NP;
  float tr = 0.f, ti = 0.f;
  #pragma unroll
  for (int j = 0; j < 9; ++j){
    float w = bk[i*9+j];
    tr += w * e9[v*9+j];
    ti += w * e9[E9SZ + v*9+j];
  }
  T[idx] = tr; T[9*NP + idx] = ti;
}

// transposed blur OTF via T-table: otfT[v*NP+u] = otf(u,v)
__global__ __launch_bounds__(256) void otfT2_k(const float* __restrict__ T, const float* __restrict__ e9,
                                               float* __restrict__ otre, float* __restrict__ otim){
  int idx = blockIdx.x*256 + threadIdx.x;
  if (idx >= NN) return;
  int u = idx % NP, v = idx / NP;
  float ar = 0.f, ai = 0.f;
  #pragma unroll
  for (int i = 0; i < 9; ++i){
    float er = e9[u*9+i], ei = e9[E9SZ + u*9+i];
    float tr = T[i*NP+v], ti = T[9*NP + i*NP+v];
    ar += er*tr - ei*ti;
    ai += er*ti + ei*tr;
  }
  otre[idx] = ar; otim[idx] = ai;
}

__global__ void taper_r_k(const float* __restrict__ bk, float* __restrict__ r_row, float* __restrict__ r_col){
  int t = threadIdx.x;
  if (t >= 18) return;
  int k = t % 9;
  bool rowp = (t < 9);
  float proj[9];
  for (int m = 0; m < 9; ++m){
    float a = 0.f;
    for (int j = 0; j < 9; ++j) a += rowp ? bk[m*9+j] : bk[j*9+m];
    proj[m] = a;
  }
  float acc = 0.f;
  for (int m = 0; m + k < 9; ++m) acc += proj[m] * proj[m+k];
  (rowp ? r_row : r_col)[k] = acc;
}

__global__ void norm_w_k(const float* __restrict__ cw, const float* __restrict__ scale,
                         float* __restrict__ wn){
  int idx = blockIdx.x*blockDim.x + threadIdx.x;
  if (idx >= ND*NF) return;
  const float* wp = cw + idx*25;
  float mean = 0.f;
  for (int k = 0; k < 25; ++k) mean += wp[k];
  mean *= (1.0f/25.0f);
  float ss = 0.f;
  for (int k = 0; k < 25; ++k){ float d = wp[k]-mean; ss += d*d; }
  float sc = scale[idx] / sqrtf(ss);
  for (int k = 0; k < 25; ++k) wn[idx*25+k] = (wp[k]-mean)*sc;
}

// filter autocorrelation: R[d][di+4][dj+4] = sum_f sum_ij w[i,j]*w[i-di,j-dj]
__global__ void R_k(const float* __restrict__ wn, float* __restrict__ R){
  int idx = blockIdx.x*blockDim.x + threadIdx.x;
  if (idx >= ND*81) return;
  int d = idx / 81, t = idx % 81;
  int di = t/9 - 4, dj = t%9 - 4;
  int i0 = di > 0 ? di : 0, i1 = di < 0 ? 4+di : 4;
  int j0 = dj > 0 ? dj : 0, j1 = dj < 0 ? 4+dj : 4;
  float acc = 0.f;
  for (int f = 0; f < NF; ++f){
    const float* w = wn + (d*NF+f)*25;
    for (int i = i0; i <= i1; ++i)
      for (int j = j0; j <= j1; ++j)
        acc += w[i*5+j] * w[(i-di)*5 + (j-dj)];
  }
  R[idx] = acc;
}

// C table: C[d][t][v] = sum_s R[d][t][s] * e_v[s-4]  (complex)
__global__ void C_k(const float* __restrict__ R, const float* __restrict__ e9,
                    float* __restrict__ Ctab){
  int idx = blockIdx.x*blockDim.x + threadIdx.x;
  if (idx >= ND*9*NP) return;
  int v = idx % NP, t9 = idx / NP;   // t9 = d*9+t
  int d = t9 / 9, t = t9 % 9;
  float cr = 0.f, ci = 0.f;
  #pragma unroll
  for (int s = 0; s < 9; ++s){
    float r = R[d*81 + t*9 + s];
    cr += r * e9[v*9+s];
    ci += r * e9[E9SZ + v*9+s];
  }
  Ctab[idx] = cr; Ctab[CSZ + idx] = ci;
}

// wiener masks MT_d = conj(otfT)/denT with inline S (from C table) + fused cvar reduction
__global__ __launch_bounds__(256) void denomMTcvar_k(
    const float* __restrict__ otre, const float* __restrict__ otim,
    const float* __restrict__ Ctab, const float* __restrict__ e9,
    const float* __restrict__ alpha,
    float* __restrict__ MTre, float* __restrict__ MTim, float* __restrict__ cvar){
  __shared__ float red[256];
  const int d = blockIdx.y;
  const int p = blockIdx.x*256 + threadIdx.x;
  float contrib = 0.f;
  if (p < NN){
    int u = p % NP, v = p / NP;
    float S = 0.f;
    #pragma unroll
    for (int t = 0; t < 9; ++t){
      float er = e9[u*9+t], ei = e9[E9SZ + u*9+t];
      float cr = Ctab[(d*9+t)*NP + v], ci = Ctab[CSZ + (d*9+t)*NP + v];
      S += er*cr - ei*ci;
    }
    float orv = otre[p], oiv = otim[p];
    float B2 = orv*orv + oiv*oiv;
    size_t idx = (size_t)d*NN + p;
    float dv = B2 + expf(alpha[d]) * S;
    MTre[idx] = orv / dv;
    MTim[idx] = -oiv / dv;
    contrib = B2 / (dv*dv);
  }
  red[threadIdx.x] = contrib; __syncthreads();
  for (int s = 128; s > 0; s >>= 1){
    if (threadIdx.x < s) red[threadIdx.x] += red[threadIdx.x+s];
    __syncthreads();
  }
  if (threadIdx.x == 0) atomicAdd(&cvar[d], red[0]);
}

__global__ void cstdn_k(const float* __restrict__ stdn, const float* __restrict__ cvar,
                        float* __restrict__ out){
  int t = threadIdx.x;
  if (t >= NB*ND) return;
  int b = t >> 2, d = t & 3;
  float s = stdn[b];
  out[(size_t)NB*ND*NPIX + t] = sqrtf(s*s*cvar[d]*(1.0f/(float)NN));
}

// ========== pad + edge-taper, LDS tile transpose (coalesced both sides) ==========
// slab(r,c) = xp2(I=c, J=r). Per block: 64x64 tile. Load x coalesced (lanes sweep J),
// taper/blur on border pixels, transpose via LDS, write slab rows coalesced.
__global__ __launch_bounds__(256) void pad_taper2_k(const float* __restrict__ x,
                                                    const float* __restrict__ bk,
                                                    const float* __restrict__ r_row,
                                                    const float* __restrict__ r_col,
                                                    u16* __restrict__ MA){
  __shared__ float tile[64][65];
  const int q  = blockIdx.z;
  const int r0 = blockIdx.y * 64;   // slab rows  (= J range)
  const int c0 = blockIdx.x * 64;   // slab cols  (= I range)
  const int t  = threadIdx.x;
  const float* xq = x + (size_t)q*NPIX;
  auto XP = [&](int ii, int jj)->float{
    int si = ii - 4; si = (si < 0) ? (-si-1) : ((si >= HH) ? (2*HH-1-si) : si);
    int sj = jj - 4; sj = (sj < 0) ? (-sj-1) : ((sj >= HH) ? (2*HH-1-sj) : sj);
    return xq[(size_t)si*HH + sj];
  };
  const float rr0 = r_row[0], rc0 = r_col[0];

  // load phase: lanes sweep J (contiguous), 4 rows per pass
  const int jl = t & 63, ib = t >> 6;
  #pragma unroll 1
  for (int pass = 0; pass < 16; ++pass){
    int il = ib + pass*4;
    int I = c0 + il, J = r0 + jl;
    float v = 0.f;
    if (I < NP && J < NP){
      v = XP(I, J);
      if (I < 9 || I >= 511 || J < 9 || J >= 511){
        float brv = (I < 9) ? r_row[I] : ((I >= 511) ? r_row[519-I] : 0.f);
        float bcv = (J < 9) ? r_col[J] : ((J >= 511) ? r_col[519-J] : 0.f);
        brv /= rr0; bcv /= rc0;
        float tp = (1.f - brv) * (1.f - bcv);
        float blur = 0.f;
        for (int a = 0; a < 9; ++a){
          int ii = wrap520(I - a + 4);
          for (int b2 = 0; b2 < 9; ++b2){
            int jj = wrap520(J - b2 + 4);
            blur += bk[a*9+b2] * XP(ii, jj);
          }
        }
        v = tp*v + (1.f - tp)*blur;
      }
    }
    tile[il][jl] = v;
  }
  __syncthreads();

  // write phase: slab rows coalesced; transpose read from LDS (2-way bank, free)
  const int cchunk = t & 7, rb = t >> 3;
  const int pair = q >> 1, im = q & 1;
  #pragma unroll
  for (int half = 0; half < 2; ++half){
    int rl = rb + half*32;
    int r = r0 + rl, cg = c0 + cchunk*8;
    if (r >= NP || cg >= NP) continue;
    bf16x8 vh, vl;
    #pragma unroll
    for (int e = 0; e < 8; ++e){
      u16 h, lo; split2(tile[cchunk*8+e][rl], h, lo);
      vh[e] = (short)h; vl[e] = (short)lo;
    }
    size_t o = (size_t)pair*PLANE + (size_t)r*KS + cg;
    *(bf16x8*)(MA + (size_t)(im*2+0)*S8P + o) = vh;
    *(bf16x8*)(MA + (size_t)(im*2+1)*S8P + o) = vl;
  }
}

// ================= MFMA complex GEMM: OUT(m,n) = sum_k P(m,k)*Q(n,k) =================
// PW=1: P is W (2 planes), Q is data (4 planes). PW=0: P data, Q is W.
// QMASK=1 (requires PW=1): Q element (n,k) is multiplied by complex mask MT[n*NP+k]
// on load (reg-staged, f32 math, split2 to LDS).
template<int PW, int CROP, int QMASK>
__global__ __launch_bounds__(256) void gemm_k(
    const u16* __restrict__ P, size_t pPlane, size_t pPair,
    const u16* __restrict__ Q, size_t qPlane, size_t qPair,
    u16* __restrict__ O, float* __restrict__ cropOut, int dIdx,
    const float* __restrict__ QMre, const float* __restrict__ QMim)
{
  constexpr int NPP = PW ? 2 : 4;
  constexpr int NPQ = PW ? 4 : 2;
  __shared__ u16 lds[(NPP+NPQ)*2048];   // planes x [64 rows][32 k] bf16
  const int tid = threadIdx.x;
  const int l = tid & 63, w = tid >> 6;
  const int b = blockIdx.z;
  const int R0 = blockIdx.y * 64, C0 = blockIdx.x * 64;

  const int rt = w*16 + (l >> 2);
  const int csrc = (l & 3) ^ ((rt >> 1) & 3);
  const size_t pOff = (size_t)b*pPair + (size_t)(R0+rt)*KS + (size_t)(csrc*8);
  const size_t qOff = (size_t)b*qPair + (size_t)(C0+rt)*KS + (size_t)(csrc*8);
  u16* ldsW = lds + w*512;

  const int lm = l & 15, lc = l >> 4;
  const int wm = w >> 1, wn = w & 1;

  f32x4 zero4 = {0.f, 0.f, 0.f, 0.f};
  f32x4 aRe[2][2], aIm[2][2];
  #pragma unroll
  for (int i = 0; i < 2; ++i)
    #pragma unroll
    for (int j = 0; j < 2; ++j){ aRe[i][j] = zero4; aIm[i][j] = zero4; }

  #pragma unroll 1
  for (int k0 = 0; k0 < KS; k0 += 32){
    #pragma unroll
    for (int p = 0; p < NPP; ++p)
      gll16(P + (size_t)p*pPlane + pOff + k0, ldsW + p*2048);
    if (QMASK){
      // reg-stage Q with complex mask applied (f32), then split2 -> LDS
      const int n = C0 + rt;
      const int kcol = k0 + csrc*8;
      bf16x8 outp0, outp1, outp2, outp3;
      if (n < NP && kcol < NP){
        size_t qo = qOff + k0;
        bf16x8 rh = *(const bf16x8*)(Q + 0*qPlane + qo);
        bf16x8 rl = *(const bf16x8*)(Q + 1*qPlane + qo);
        bf16x8 ih = *(const bf16x8*)(Q + 2*qPlane + qo);
        bf16x8 il = *(const bf16x8*)(Q + 3*qPlane + qo);
        const float* mrp = QMre + (size_t)n*NP + kcol;
        const float* mip = QMim + (size_t)n*NP + kcol;
        f32x4 mr0 = *(const f32x4*)(mrp); f32x4 mr1 = *(const f32x4*)(mrp+4);
        f32x4 mi0 = *(const f32x4*)(mip); f32x4 mi1 = *(const f32x4*)(mip+4);
        #pragma unroll
        for (int e = 0; e < 8; ++e){
          float mr = (e < 4) ? mr0[e] : mr1[e-4];
          float mi = (e < 4) ? mi0[e] : mi1[e-4];
          float vr = rec((u16)rh[e], (u16)rl[e]);
          float vi = rec((u16)ih[e], (u16)il[e]);
          float wr = vr*mr - vi*mi;
          float wi = vr*mi + vi*mr;
          u16 h, lo;
          split2(wr, h, lo); outp0[e] = (short)h; outp1[e] = (short)lo;
          split2(wi, h, lo); outp2[e] = (short)h; outp3[e] = (short)lo;
        }
      } else {
        #pragma unroll
        for (int e = 0; e < 8; ++e){ outp0[e]=0; outp1[e]=0; outp2[e]=0; outp3[e]=0; }
      }
      *(bf16x8*)(lds + (NPP+0)*2048 + w*512 + l*8) = outp0;
      *(bf16x8*)(lds + (NPP+1)*2048 + w*512 + l*8) = outp1;
      *(bf16x8*)(lds + (NPP+2)*2048 + w*512 + l*8) = outp2;
      *(bf16x8*)(lds + (NPP+3)*2048 + w*512 + l*8) = outp3;
    } else {
      #pragma unroll
      for (int p = 0; p < NPQ; ++p)
        gll16(Q + (size_t)p*qPlane + qOff + k0, ldsW + (NPP+p)*2048);
    }
    __syncthreads();

    bf16x8 pf[2][NPP], qf[2][NPQ];
    #pragma unroll
    for (int mi = 0; mi < 2; ++mi){
      int r = wm*32 + mi*16 + lm;
      int co = ((lc ^ ((r >> 1) & 3)) << 3);
      #pragma unroll
      for (int p = 0; p < NPP; ++p)
        pf[mi][p] = *(const bf16x8*)(lds + p*2048 + r*32 + co);
    }
    #pragma unroll
    for (int ni = 0; ni < 2; ++ni){
      int r = wn*32 + ni*16 + lm;
      int co = ((lc ^ ((r >> 1) & 3)) << 3);
      #pragma unroll
      for (int p = 0; p < NPQ; ++p)
        qf[ni][p] = *(const bf16x8*)(lds + (NPP+p)*2048 + r*32 + co);
    }

    if (PW){
      // P = W{re,im}; Q = data{rh,rl,ih,il}
      #pragma unroll
      for (int mi = 0; mi < 2; ++mi){
        bf16x8 nw1 = pf[mi][1] ^ (short)0x8000;   // -W.im
        #pragma unroll
        for (int ni = 0; ni < 2; ++ni){
          f32x4 r = aRe[mi][ni], im = aIm[mi][ni];
          r  = MF(pf[mi][0], qf[ni][0], r);
          r  = MF(pf[mi][0], qf[ni][1], r);
          r  = MF(nw1,       qf[ni][2], r);
          r  = MF(nw1,       qf[ni][3], r);
          im = MF(pf[mi][0], qf[ni][2], im);
          im = MF(pf[mi][0], qf[ni][3], im);
          im = MF(pf[mi][1], qf[ni][0], im);
          im = MF(pf[mi][1], qf[ni][1], im);
          aRe[mi][ni] = r; aIm[mi][ni] = im;
        }
      }
    } else {
      // P = data{rh,rl,ih,il}; Q = W{re,im}
      #pragma unroll
      for (int ni = 0; ni < 2; ++ni){
        bf16x8 nw1 = qf[ni][1] ^ (short)0x8000;   // -W.im
        #pragma unroll
        for (int mi = 0; mi < 2; ++mi){
          f32x4 r = aRe[mi][ni], im = aIm[mi][ni];
          r  = MF(pf[mi][0], qf[ni][0], r);
          r  = MF(pf[mi][1], qf[ni][0], r);
          r  = MF(pf[mi][2], nw1,       r);
          r  = MF(pf[mi][3], nw1,       r);
          im = MF(pf[mi][0], qf[ni][1], im);
          im = MF(pf[mi][1], qf[ni][1], im);
          im = MF(pf[mi][2], qf[ni][0], im);
          im = MF(pf[mi][3], qf[ni][0], im);
          aRe[mi][ni] = r; aIm[mi][ni] = im;
        }
      }
    }
    __syncthreads();
  }

  // epilogue
  #pragma unroll
  for (int mi = 0; mi < 2; ++mi)
    #pragma unroll
    for (int ni = 0; ni < 2; ++ni){
      int cb = C0 + wn*32 + ni*16 + lm;
      int rb = R0 + wm*32 + mi*16 + lc*4;
      #pragma unroll
      for (int e = 0; e < 4; ++e){
        int rr = rb + e;
        float vr = aRe[mi][ni][e], vi = aIm[mi][ni][e];
        if (CROP){
          if (rr >= 4 && rr < 516 && cb >= 4 && cb < 516){
            size_t px = (size_t)(rr-4)*HH + (cb-4);
            cropOut[((size_t)(2*b  )*ND + dIdx)*NPIX + px] = vr;
            cropOut[((size_t)(2*b+1)*ND + dIdx)*NPIX + px] = vi;
          }
        } else {
          if (rr < NP && cb < NP){
            size_t o = (size_t)b*PLANE + (size_t)rr*KS + cb;
            u16 h, lo;
            split2(vr, h, lo); O[0*S8P+o] = h; O[1*S8P+o] = lo;
            split2(vi, h, lo); O[2*S8P+o] = h; O[3*S8P+o] = lo;
          }
        }
      }
    }
}

// ================= host =================

extern "C" void kernel_launch(void* const* d_in, const int* in_sizes, int n_in,
                              void* d_out, int out_size, void* d_ws, size_t ws_size,
                              hipStream_t stream){
  const float* x     = (const float*)d_in[0];
  const float* bk    = (const float*)d_in[1];
  const float* stdn  = (const float*)d_in[2];
  const float* cw    = (const float*)d_in[3];
  const float* scale = (const float*)d_in[4];
  const float* alpha = (const float*)d_in[5];
  float* out = (float*)d_out;

  char* base = (char*)d_ws;
  size_t off = 0;
  auto alloc = [&](size_t bytes)->void*{
    void* p = base + off;
    off += (bytes + 255) & ~(size_t)255;
    return p;
  };
  u16* MA = (u16*)alloc(4*S8P*sizeof(u16));
  u16* MB = (u16*)alloc(4*S8P*sizeof(u16));
  u16* MC = (u16*)alloc(4*S8P*sizeof(u16));
  u16* WF = (u16*)alloc(2*PLANE*sizeof(u16));
  u16* WI = (u16*)alloc(2*PLANE*sizeof(u16));
  size_t zeroBytes = off;   // slabs + W memset to 0 (padded regions must be 0)
  float* otre = (float*)alloc(NN*4);
  float* otim = (float*)alloc(NN*4);
  float* MTre = (float*)alloc((size_t)ND*NN*4);
  float* MTim = (float*)alloc((size_t)ND*NN*4);
  float* e9   = (float*)alloc(2*E9SZ*4);
  float* Tb   = (float*)alloc(2*9*NP*4);
  float* Rarr = (float*)alloc(ND*81*4);
  float* Ctab = (float*)alloc(2*CSZ*4);
  float* r_row = (float*)alloc(64);
  float* r_col = (float*)alloc(64);
  float* wn   = (float*)alloc(ND*NF*25*4);
  float* cvar = (float*)alloc(64);
  if (off > ws_size) return;  // insufficient workspace

  hipMemsetAsync(d_ws, 0, zeroBytes, stream);
  hipMemsetAsync(cvar, 0, ND*sizeof(float), stream);

  build_Wpair_k<<<((int)PLANE+255)/256, 256, 0, stream>>>(WF, WI);
  e9_k         <<<(NP*9+255)/256, 256, 0, stream>>>(e9);
  taper_r_k    <<<1, 32, 0, stream>>>(bk, r_row, r_col);
  norm_w_k     <<<1, 128, 0, stream>>>(cw, scale, wn);
  bkT_k        <<<(9*NP+255)/256, 256, 0, stream>>>(bk, e9, Tb);
  R_k          <<<2, 256, 0, stream>>>(wn, Rarr);
  otfT2_k      <<<(NN+255)/256, 256, 0, stream>>>(Tb, e9, otre, otim);
  C_k          <<<(ND*9*NP+255)/256, 256, 0, stream>>>(Rarr, e9, Ctab);
  {
    dim3 gd((NN+255)/256, ND);
    denomMTcvar_k<<<gd, 256, 0, stream>>>(otre, otim, Ctab, e9, alpha, MTre, MTim, cvar);
  }
  cstdn_k      <<<1, 64, 0, stream>>>(stdn, cvar, out);
  pad_taper2_k <<<dim3(9, 9, NB), 256, 0, stream>>>(x, bk, r_row, r_col, MA);

  dim3 gg(9, 9, NPAIR);
  const size_t BP = S8P, BW = PLANE;
  // fft2(xp2): C5 = W*xp2   (P=Wf, Q=xp2T)   -> MB
  gemm_k<1,0,0><<<gg,256,0,stream>>>(WF,BW,0, MA,BP,PLANE, MB, nullptr, 0, nullptr, nullptr);
  // F2^T                    (P=Wf, Q=C5)     -> MC
  gemm_k<1,0,0><<<gg,256,0,stream>>>(WF,BW,0, MB,BP,PLANE, MC, nullptr, 0, nullptr, nullptr);
  for (int d = 0; d < ND; ++d){
    // C7 = Wi*(F2^T .* MT_d)  (P=Wi, Q=MC masked) -> MA
    gemm_k<1,0,1><<<gg,256,0,stream>>>(WI,BW,0, MC,BP,PLANE, MA, nullptr, 0,
                                       MTre + (size_t)d*NN, MTim + (size_t)d*NN);
    // out_d = C7*Wi (crop)    (P=C7, Q=Wi)
    gemm_k<0,1,0><<<gg,256,0,stream>>>(MA,BP,PLANE, WI,BW,0, nullptr, out, d, nullptr, nullptr);
  }
}